// Round 14
// baseline (253.598 us; speedup 1.0000x reference)
//
#include <hip/hip_runtime.h>

#define N_NODES 100000
#define N_EDGES 1600000
#define IN_C    128
#define OUT_C   64

#define SB_NODES 512                               // nodes per super-bucket
#define NSB  ((N_NODES + SB_NODES - 1) / SB_NODES) // 196
#define SCAP 9216                                  // mean 8163, +11 sigma
#define ACHUNK 4096                                // edges per sorta block
#define NABLK ((N_EDGES + ACHUNK - 1) / ACHUNK)    // 391

// ---- bf16x2 helpers ----
__device__ inline unsigned pack_bf16x2(float lo, float hi) {
    unsigned a = __float_as_uint(lo), b2 = __float_as_uint(hi);
    a  += 0x7fff + ((a  >> 16) & 1);               // RNE
    b2 += 0x7fff + ((b2 >> 16) & 1);
    return (a >> 16) | (b2 & 0xffff0000u);
}
__device__ inline float bf_lo(unsigned v) { return __uint_as_float(v << 16); }
__device__ inline float bf_hi(unsigned v) { return __uint_as_float(v & 0xffff0000u); }

// ---------------- zero super-bucket cursors ----------------
__global__ void zero_kernel(int* __restrict__ cursor) {
    int i = blockIdx.x * blockDim.x + threadIdx.x;
    if (i < NSB) cursor[i] = 0;
}

// ------ pass A: partition edges into 196 coarse dst-buckets (512 nodes) -----
// 1024 threads (neutral vs 256t, kept)
__global__ __launch_bounds__(1024) void sorta_kernel(const int* __restrict__ ei,
                                                     int* __restrict__ cursor,
                                                     int* __restrict__ sb) {
    __shared__ int histW[16][NSB];
    __shared__ int base_[NSB];
    __shared__ int cur[NSB];
    const int t = threadIdx.x, w = t >> 6;
    const long long e0 = (long long)blockIdx.x * ACHUNK;
    for (int i = t; i < 16 * NSB; i += 1024) (&histW[0][0])[i] = 0;
    __syncthreads();
    const int* dsts = ei + N_EDGES;
    {
        long long i4 = e0 / 4 + t;                 // 1024 threads x int4 = 4096 edges
        if (i4 * 4 + 3 < N_EDGES) {
            int4 d = *(const int4*)&dsts[i4 * 4];
            atomicAdd(&histW[w][d.x >> 9], 1);
            atomicAdd(&histW[w][d.y >> 9], 1);
            atomicAdd(&histW[w][d.z >> 9], 1);
            atomicAdd(&histW[w][d.w >> 9], 1);
        }
    }
    __syncthreads();
    if (t < NSB) {
        int c = 0;
#pragma unroll
        for (int v = 0; v < 16; ++v) c += histW[v][t];
        base_[t] = c ? atomicAdd(&cursor[t], c) : 0;
        cur[t] = 0;
    }
    __syncthreads();
    {
        long long i4 = e0 / 4 + t;
        if (i4 * 4 + 3 < N_EDGES) {
            int4 s4 = *(const int4*)&ei[i4 * 4];
            int4 d4 = *(const int4*)&dsts[i4 * 4];
            int sv[4] = {s4.x, s4.y, s4.z, s4.w};
            int dv[4] = {d4.x, d4.y, d4.z, d4.w};
#pragma unroll
            for (int j = 0; j < 4; ++j) {
                int bk = dv[j] >> 9;
                int pos = base_[bk] + atomicAdd(&cur[bk], 1);
                if (pos < SCAP)
                    sb[bk * SCAP + pos] = sv[j] * SB_NODES + (dv[j] & (SB_NODES - 1));
            }
        }
    }
}

// ------ pass B: per coarse bucket, LDS counting sort by node -> CSR ---------
// 1024 threads (R11-verified win: -8.1 us vs 256t)
__global__ __launch_bounds__(1024) void sortb_kernel(const int* __restrict__ cursor,
                                                     int* __restrict__ sb,
                                                     float* __restrict__ dinv,
                                                     int* __restrict__ rowbeg,
                                                     int* __restrict__ rowend) {
    __shared__ int hist[SB_NODES];
    __shared__ int pref[SB_NODES + 1];
    __shared__ int cur[SB_NODES];
    __shared__ int sc[SB_NODES];
    __shared__ int sorted[SCAP];                   // 36.9 KB (total ~45 KB)
    const int t = threadIdx.x, b = blockIdx.x;
    if (t < SB_NODES) { hist[t] = 0; cur[t] = 0; }
    __syncthreads();
    int m = cursor[b]; if (m > SCAP) m = SCAP;
    int* bb = sb + b * SCAP;
    for (int i = t; i < m; i += 1024) atomicAdd(&hist[bb[i] & (SB_NODES - 1)], 1);
    __syncthreads();
    if (t < SB_NODES) sc[t] = hist[t];
    __syncthreads();
    for (int off = 1; off < SB_NODES; off <<= 1) { // Hillis-Steele inclusive
        int u = 0;
        if (t < SB_NODES && t >= off) u = sc[t - off];
        __syncthreads();
        if (t < SB_NODES) sc[t] += u;
        __syncthreads();
    }
    if (t < SB_NODES) pref[t] = sc[t] - hist[t];   // exclusive
    if (t == SB_NODES - 1) pref[SB_NODES] = sc[SB_NODES - 1];
    __syncthreads();
    for (int i = t; i < m; i += 1024) {
        int e = bb[i];
        int dl = e & (SB_NODES - 1);
        int pos = pref[dl] + atomicAdd(&cur[dl], 1);
        sorted[pos] = e >> 9;                      // plain src id
    }
    __syncthreads();
    for (int i = t; i < m; i += 1024) bb[i] = sorted[i];  // coalesced writeback
    if (t < SB_NODES) {
        int n = b * SB_NODES + t;
        if (n < N_NODES) {
            rowbeg[n] = b * SCAP + pref[t];
            rowend[n] = b * SCAP + pref[t + 1];
            dinv[n]   = rsqrtf((float)hist[t] + 1.0f);    // +1 self-loop
        }
    }
}

// ------- xws = bf16( dinv[n] * (x @ W) ) : 32 nodes/block, 128 B rows -------
#define XN  32
#define SXS 132
__global__ __launch_bounds__(256) void xws_kernel(const float* __restrict__ x,
                                                  const float* __restrict__ W,
                                                  const float* __restrict__ dinv,
                                                  unsigned* __restrict__ xwsh) {
    __shared__ float sW[IN_C * OUT_C];     // 32 KB
    __shared__ float sx[XN * SXS];         // 16.9 KB
    const int t = threadIdx.x;
    const int n0 = blockIdx.x * XN;
    const float4* W4 = (const float4*)W;
    float4* sW4 = (float4*)sW;
#pragma unroll
    for (int k = 0; k < 8; ++k) sW4[t + k * 256] = W4[t + k * 256];
#pragma unroll
    for (int k = 0; k < 4; ++k) {
        int idx = (t + k * 256) * 4;
        int r = idx >> 7, kk = idx & 127;
        int n = n0 + r;
        float4 v = (n < N_NODES) ? *(const float4*)&x[(long long)n * IN_C + kk]
                                 : make_float4(0.f, 0.f, 0.f, 0.f);
        *(float4*)&sx[r * SXS + kk] = v;
    }
    __syncthreads();
    const int r  = t >> 4;
    const int cq = (t & 15) << 2;
    float4 a0 = make_float4(0.f,0.f,0.f,0.f), a1 = a0;
#pragma unroll 8
    for (int k = 0; k < IN_C; ++k) {
        float x0 = sx[r * SXS + k];
        float x1 = sx[(r + 16) * SXS + k];
        float4 wv = *(const float4*)&sW[(k << 6) + cq];
        a0.x = fmaf(x0, wv.x, a0.x); a0.y = fmaf(x0, wv.y, a0.y);
        a0.z = fmaf(x0, wv.z, a0.z); a0.w = fmaf(x0, wv.w, a0.w);
        a1.x = fmaf(x1, wv.x, a1.x); a1.y = fmaf(x1, wv.y, a1.y);
        a1.z = fmaf(x1, wv.z, a1.z); a1.w = fmaf(x1, wv.w, a1.w);
    }
    int na = n0 + r, nb = n0 + r + 16;
    if (na < N_NODES) {
        float di = dinv[na];
        uint2 o = make_uint2(pack_bf16x2(a0.x * di, a0.y * di),
                             pack_bf16x2(a0.z * di, a0.w * di));
        *(uint2*)&xwsh[(long long)na * 32 + ((t & 15) << 1)] = o;
    }
    if (nb < N_NODES) {
        float di = dinv[nb];
        uint2 o = make_uint2(pack_bf16x2(a1.x * di, a1.y * di),
                             pack_bf16x2(a1.z * di, a1.w * di));
        *(uint2*)&xwsh[(long long)nb * 32 + ((t & 15) << 1)] = o;
    }
}

// ------- pull aggregation + fused epilogue: 2 nodes per wave ---------------
// node0 param: split x3 (~16.4 us each) lowers the top-5 visibility threshold
// so xws/sortb/sorta surface with counters (instrumentation, R6-verified).
__global__ __launch_bounds__(256) void aggnode_kernel(
    const int node0,
    const int* __restrict__ rowbeg, const int* __restrict__ rowend,
    const int* __restrict__ srcs, const float* __restrict__ dinv,
    const unsigned* __restrict__ xwsh, const float* __restrict__ b,
    const float* __restrict__ Wc, const float* __restrict__ bc,
    float2* __restrict__ p, float2* __restrict__ q) {
    const int lane = threadIdx.x & 63;
    const int hl   = lane & 31;              // lane within node-half
    const int g    = hl >> 3;                // edge slot 0..3
    const int j    = hl & 7;                 // channel octet: ch 8j..8j+7
    const unsigned woff = (unsigned)(j << 2);
    const int node = node0 + blockIdx.x * 8 + ((threadIdx.x >> 6) << 1) + (lane >> 5);
    const int beg = rowbeg[node], end = rowend[node];
    const float di = dinv[node];                                   // hoisted
    const uint4 vsl = *(const uint4*)&xwsh[((unsigned)node << 5) + woff]; // hoisted
    float a0=0.f,a1=0.f,a2=0.f,a3=0.f,a4=0.f,a5=0.f,a6=0.f,a7=0.f;
    const int m1 = end - 1;
    for (int i = beg; i < end; i += 16) {
        int e0 = i + g, e1 = e0 + 4, e2 = e0 + 8, e3 = e0 + 12;
        int i0 = min(e0, m1), i1 = min(e1, m1), i2 = min(e2, m1), i3 = min(e3, m1);
        int s0 = srcs[i0], s1 = srcs[i1], s2 = srcs[i2], s3 = srcs[i3];
        float f0 = (e0 < end) ? 1.f : 0.f;
        float f1 = (e1 < end) ? 1.f : 0.f;
        float f2 = (e2 < end) ? 1.f : 0.f;
        float f3 = (e3 < end) ? 1.f : 0.f;
        uint4 v0 = *(const uint4*)&xwsh[((unsigned)s0 << 5) + woff];
        uint4 v1 = *(const uint4*)&xwsh[((unsigned)s1 << 5) + woff];
        uint4 v2 = *(const uint4*)&xwsh[((unsigned)s2 << 5) + woff];
        uint4 v3 = *(const uint4*)&xwsh[((unsigned)s3 << 5) + woff];
        a0 = fmaf(f0, bf_lo(v0.x), a0); a1 = fmaf(f0, bf_hi(v0.x), a1);
        a2 = fmaf(f0, bf_lo(v0.y), a2); a3 = fmaf(f0, bf_hi(v0.y), a3);
        a4 = fmaf(f0, bf_lo(v0.z), a4); a5 = fmaf(f0, bf_hi(v0.z), a5);
        a6 = fmaf(f0, bf_lo(v0.w), a6); a7 = fmaf(f0, bf_hi(v0.w), a7);
        a0 = fmaf(f1, bf_lo(v1.x), a0); a1 = fmaf(f1, bf_hi(v1.x), a1);
        a2 = fmaf(f1, bf_lo(v1.y), a2); a3 = fmaf(f1, bf_hi(v1.y), a3);
        a4 = fmaf(f1, bf_lo(v1.z), a4); a5 = fmaf(f1, bf_hi(v1.z), a5);
        a6 = fmaf(f1, bf_lo(v1.w), a6); a7 = fmaf(f1, bf_hi(v1.w), a7);
        a0 = fmaf(f2, bf_lo(v2.x), a0); a1 = fmaf(f2, bf_hi(v2.x), a1);
        a2 = fmaf(f2, bf_lo(v2.y), a2); a3 = fmaf(f2, bf_hi(v2.y), a3);
        a4 = fmaf(f2, bf_lo(v2.z), a4); a5 = fmaf(f2, bf_hi(v2.z), a5);
        a6 = fmaf(f2, bf_lo(v2.w), a6); a7 = fmaf(f2, bf_hi(v2.w), a7);
        a0 = fmaf(f3, bf_lo(v3.x), a0); a1 = fmaf(f3, bf_hi(v3.x), a1);
        a2 = fmaf(f3, bf_lo(v3.y), a2); a3 = fmaf(f3, bf_hi(v3.y), a3);
        a4 = fmaf(f3, bf_lo(v3.z), a4); a5 = fmaf(f3, bf_hi(v3.z), a5);
        a6 = fmaf(f3, bf_lo(v3.w), a6); a7 = fmaf(f3, bf_hi(v3.w), a7);
    }
    a0 += __shfl_xor(a0, 8); a0 += __shfl_xor(a0, 16);
    a1 += __shfl_xor(a1, 8); a1 += __shfl_xor(a1, 16);
    a2 += __shfl_xor(a2, 8); a2 += __shfl_xor(a2, 16);
    a3 += __shfl_xor(a3, 8); a3 += __shfl_xor(a3, 16);
    a4 += __shfl_xor(a4, 8); a4 += __shfl_xor(a4, 16);
    a5 += __shfl_xor(a5, 8); a5 += __shfl_xor(a5, 16);
    a6 += __shfl_xor(a6, 8); a6 += __shfl_xor(a6, 16);
    a7 += __shfl_xor(a7, 8); a7 += __shfl_xor(a7, 16);
    a0 += bf_lo(vsl.x); a1 += bf_hi(vsl.x);
    a2 += bf_lo(vsl.y); a3 += bf_hi(vsl.y);
    a4 += bf_lo(vsl.z); a5 += bf_hi(vsl.z);
    a6 += bf_lo(vsl.w); a7 += bf_hi(vsl.w);
    float4 bA = ((const float4*)b)[(j << 1)];
    float4 bB = ((const float4*)b)[(j << 1) + 1];
    float h0 = fmaxf(fmaf(di, a0, bA.x), 0.f);
    float h1 = fmaxf(fmaf(di, a1, bA.y), 0.f);
    float h2 = fmaxf(fmaf(di, a2, bA.z), 0.f);
    float h3 = fmaxf(fmaf(di, a3, bA.w), 0.f);
    float h4 = fmaxf(fmaf(di, a4, bB.x), 0.f);
    float h5 = fmaxf(fmaf(di, a5, bB.y), 0.f);
    float h6 = fmaxf(fmaf(di, a6, bB.z), 0.f);
    float h7 = fmaxf(fmaf(di, a7, bB.w), 0.f);
    const float4* WS = (const float4*)Wc;
    const float4* WD = (const float4*)(Wc + 2 * OUT_C);
    float p0, p1, q0, q1;
    {
        float4 w0 = WS[(j << 2)], w1 = WS[(j << 2) + 1];
        float4 w2 = WS[(j << 2) + 2], w3 = WS[(j << 2) + 3];
        p0 = h0 * w0.x + h1 * w0.z + h2 * w1.x + h3 * w1.z
           + h4 * w2.x + h5 * w2.z + h6 * w3.x + h7 * w3.z;
        p1 = h0 * w0.y + h1 * w0.w + h2 * w1.y + h3 * w1.w
           + h4 * w2.y + h5 * w2.w + h6 * w3.y + h7 * w3.w;
    }
    {
        float4 u0 = WD[(j << 2)], u1 = WD[(j << 2) + 1];
        float4 u2 = WD[(j << 2) + 2], u3 = WD[(j << 2) + 3];
        q0 = h0 * u0.x + h1 * u0.z + h2 * u1.x + h3 * u1.z
           + h4 * u2.x + h5 * u2.z + h6 * u3.x + h7 * u3.z;
        q1 = h0 * u0.y + h1 * u0.w + h2 * u1.y + h3 * u1.w
           + h4 * u2.y + h5 * u2.w + h6 * u3.y + h7 * u3.w;
    }
#pragma unroll
    for (int off = 1; off <= 4; off <<= 1) {
        p0 += __shfl_xor(p0, off); p1 += __shfl_xor(p1, off);
        q0 += __shfl_xor(q0, off); q1 += __shfl_xor(q1, off);
    }
    if (hl == 0) {
        p[node] = make_float2(p0 + bc[0], p1 + bc[1]);
        q[node] = make_float2(q0, q1);
    }
}

// ------------ edge outputs: out[e] = p[src] + q[dst], 4 edges/thread --------
// One edge list per launch (pos/neg split: instrumentation, zero code risk)
__global__ void edge_kernel(const int* __restrict__ E,
                            const float2* __restrict__ p, const float2* __restrict__ q,
                            float4* __restrict__ out4) {
    int idx = blockIdx.x * blockDim.x + threadIdx.x;
    if (idx >= N_EDGES / 4) return;
    int off = idx * 4;
    const int* S = E;
    const int* D = E + N_EDGES;
    int4 s4 = *(const int4*)&S[off];
    int4 d4 = *(const int4*)&D[off];
    float2 pa = p[s4.x], qa = q[d4.x];
    float2 pb = p[s4.y], qb = q[d4.y];
    float2 pc = p[s4.z], qc = q[d4.z];
    float2 pd = p[s4.w], qd = q[d4.w];
    out4[idx * 2]     = make_float4(pa.x + qa.x, pa.y + qa.y, pb.x + qb.x, pb.y + qb.y);
    out4[idx * 2 + 1] = make_float4(pc.x + qc.x, pc.y + qc.y, pd.x + qd.x, pd.y + qd.y);
}

extern "C" void kernel_launch(void* const* d_in, const int* in_sizes, int n_in,
                              void* d_out, int out_size, void* d_ws, size_t ws_size,
                              hipStream_t stream) {
    const float* x   = (const float*)d_in[0];   // [N,128]
    const int*   ei  = (const int*)  d_in[1];   // [2,E]
    const int*   nei = (const int*)  d_in[2];   // [2,E]
    const float* W   = (const float*)d_in[3];   // [128,64]
    const float* b   = (const float*)d_in[4];   // [64]
    const float* Wc  = (const float*)d_in[5];   // [128,2]
    const float* bc  = (const float*)d_in[6];   // [2]

    // workspace (ints): end = 3902720 + 196*9216 = 5709056 ints = 22.8 MB
    int*      wsI    = (int*)d_ws;
    float*    dinv   = (float*)wsI;              // N           [0, 100352)
    unsigned* xwsh   = (unsigned*)(wsI + 100352);// N*32 bf16x2 [100352, 3300352)
    float*    p      = (float*)(wsI + 3300352);  // N*2         [3300352, 3501056)
    float*    q      = (float*)(wsI + 3501056);  // N*2         [3501056, 3701760)
    int*      cursor = wsI + 3701760;            // NSB         [3701760, 3702016)
    int*      rowbeg = wsI + 3702016;            // N           [3702016, 3802368)
    int*      rowend = wsI + 3802368;            // N           [3802368, 3902720)
    int*      sbuf   = wsI + 3902720;            // NSB*SCAP

    const int B = 256;
    zero_kernel<<<1, B, 0, stream>>>(cursor);
    sorta_kernel<<<NABLK, 1024, 0, stream>>>(ei, cursor, sbuf);
    sortb_kernel<<<NSB, 1024, 0, stream>>>(cursor, sbuf, dinv, rowbeg, rowend);
    xws_kernel<<<(N_NODES + XN - 1) / XN, B, 0, stream>>>(x, W, dinv, xwsh);
    // aggnode split x3 (instrumentation): nodes [0,33336) [33336,66672) [66672,100000)
    aggnode_kernel<<<4167, B, 0, stream>>>(0,     rowbeg, rowend, sbuf, dinv, xwsh,
                                           b, Wc, bc, (float2*)p, (float2*)q);
    aggnode_kernel<<<4167, B, 0, stream>>>(33336, rowbeg, rowend, sbuf, dinv, xwsh,
                                           b, Wc, bc, (float2*)p, (float2*)q);
    aggnode_kernel<<<4166, B, 0, stream>>>(66672, rowbeg, rowend, sbuf, dinv, xwsh,
                                           b, Wc, bc, (float2*)p, (float2*)q);
    // edge split pos/neg (instrumentation): each writes its own half of out
    edge_kernel<<<(N_EDGES / 4 + B - 1) / B, B, 0, stream>>>(
        ei,  (const float2*)p, (const float2*)q, (float4*)d_out);
    edge_kernel<<<(N_EDGES / 4 + B - 1) / B, B, 0, stream>>>(
        nei, (const float2*)p, (const float2*)q, (float4*)d_out + N_EDGES / 2);
}

// Round 15
// 245.058 us; speedup vs baseline: 1.0348x; 1.0348x over previous
//
#include <hip/hip_runtime.h>

#define N_NODES 100000
#define N_EDGES 1600000
#define IN_C    128
#define OUT_C   64

#define SB_NODES 512                               // nodes per super-bucket
#define NSB  ((N_NODES + SB_NODES - 1) / SB_NODES) // 196
#define SCAP 9216                                  // mean 8163, +11 sigma
#define ACHUNK 4096                                // edges per sorta block
#define NABLK ((N_EDGES + ACHUNK - 1) / ACHUNK)    // 391

// ---- bf16x2 helpers ----
__device__ inline unsigned pack_bf16x2(float lo, float hi) {
    unsigned a = __float_as_uint(lo), b2 = __float_as_uint(hi);
    a  += 0x7fff + ((a  >> 16) & 1);               // RNE
    b2 += 0x7fff + ((b2 >> 16) & 1);
    return (a >> 16) | (b2 & 0xffff0000u);
}
__device__ inline float bf_lo(unsigned v) { return __uint_as_float(v << 16); }
__device__ inline float bf_hi(unsigned v) { return __uint_as_float(v & 0xffff0000u); }

// ---------------- zero super-bucket cursors ----------------
__global__ void zero_kernel(int* __restrict__ cursor) {
    int i = blockIdx.x * blockDim.x + threadIdx.x;
    if (i < NSB) cursor[i] = 0;
}

// ------ pass A: partition edges into 196 coarse dst-buckets (512 nodes) -----
// 1024 threads (neutral vs 256t, kept)
__global__ __launch_bounds__(1024) void sorta_kernel(const int* __restrict__ ei,
                                                     int* __restrict__ cursor,
                                                     int* __restrict__ sb) {
    __shared__ int histW[16][NSB];
    __shared__ int base_[NSB];
    __shared__ int cur[NSB];
    const int t = threadIdx.x, w = t >> 6;
    const long long e0 = (long long)blockIdx.x * ACHUNK;
    for (int i = t; i < 16 * NSB; i += 1024) (&histW[0][0])[i] = 0;
    __syncthreads();
    const int* dsts = ei + N_EDGES;
    {
        long long i4 = e0 / 4 + t;                 // 1024 threads x int4 = 4096 edges
        if (i4 * 4 + 3 < N_EDGES) {
            int4 d = *(const int4*)&dsts[i4 * 4];
            atomicAdd(&histW[w][d.x >> 9], 1);
            atomicAdd(&histW[w][d.y >> 9], 1);
            atomicAdd(&histW[w][d.z >> 9], 1);
            atomicAdd(&histW[w][d.w >> 9], 1);
        }
    }
    __syncthreads();
    if (t < NSB) {
        int c = 0;
#pragma unroll
        for (int v = 0; v < 16; ++v) c += histW[v][t];
        base_[t] = c ? atomicAdd(&cursor[t], c) : 0;
        cur[t] = 0;
    }
    __syncthreads();
    {
        long long i4 = e0 / 4 + t;
        if (i4 * 4 + 3 < N_EDGES) {
            int4 s4 = *(const int4*)&ei[i4 * 4];
            int4 d4 = *(const int4*)&dsts[i4 * 4];
            int sv[4] = {s4.x, s4.y, s4.z, s4.w};
            int dv[4] = {d4.x, d4.y, d4.z, d4.w};
#pragma unroll
            for (int j = 0; j < 4; ++j) {
                int bk = dv[j] >> 9;
                int pos = base_[bk] + atomicAdd(&cur[bk], 1);
                if (pos < SCAP)
                    sb[bk * SCAP + pos] = sv[j] * SB_NODES + (dv[j] & (SB_NODES - 1));
            }
        }
    }
}

// ------ pass B: per coarse bucket, LDS counting sort by node -> CSR ---------
// 1024 threads (R11-verified win: -8.1 us vs 256t)
__global__ __launch_bounds__(1024) void sortb_kernel(const int* __restrict__ cursor,
                                                     int* __restrict__ sb,
                                                     float* __restrict__ dinv,
                                                     int* __restrict__ rowbeg,
                                                     int* __restrict__ rowend) {
    __shared__ int hist[SB_NODES];
    __shared__ int pref[SB_NODES + 1];
    __shared__ int cur[SB_NODES];
    __shared__ int sc[SB_NODES];
    __shared__ int sorted[SCAP];                   // 36.9 KB (total ~45 KB)
    const int t = threadIdx.x, b = blockIdx.x;
    if (t < SB_NODES) { hist[t] = 0; cur[t] = 0; }
    __syncthreads();
    int m = cursor[b]; if (m > SCAP) m = SCAP;
    int* bb = sb + b * SCAP;
    for (int i = t; i < m; i += 1024) atomicAdd(&hist[bb[i] & (SB_NODES - 1)], 1);
    __syncthreads();
    if (t < SB_NODES) sc[t] = hist[t];
    __syncthreads();
    for (int off = 1; off < SB_NODES; off <<= 1) { // Hillis-Steele inclusive
        int u = 0;
        if (t < SB_NODES && t >= off) u = sc[t - off];
        __syncthreads();
        if (t < SB_NODES) sc[t] += u;
        __syncthreads();
    }
    if (t < SB_NODES) pref[t] = sc[t] - hist[t];   // exclusive
    if (t == SB_NODES - 1) pref[SB_NODES] = sc[SB_NODES - 1];
    __syncthreads();
    for (int i = t; i < m; i += 1024) {
        int e = bb[i];
        int dl = e & (SB_NODES - 1);
        int pos = pref[dl] + atomicAdd(&cur[dl], 1);
        sorted[pos] = e >> 9;                      // plain src id
    }
    __syncthreads();
    for (int i = t; i < m; i += 1024) bb[i] = sorted[i];  // coalesced writeback
    if (t < SB_NODES) {
        int n = b * SB_NODES + t;
        if (n < N_NODES) {
            rowbeg[n] = b * SCAP + pref[t];
            rowend[n] = b * SCAP + pref[t + 1];
            dinv[n]   = rsqrtf((float)hist[t] + 1.0f);    // +1 self-loop
        }
    }
}

// ------- xws = bf16( dinv[n] * (x @ W) ) : sW-only LDS, x direct from global
// R13 profile: 48.5 KB LDS -> 3 blocks/CU, 24% occupancy, LDS-oversubscribed
// inner loop (24 LDS-cyc / 16 FMA-cyc). v2: drop sx stage; only sW (32 KB) in
// LDS -> 5 blocks/CU (~62% occ cap). Lanes 0-15 read the SAME x address
// (broadcast, 1 transaction); each 512 B row streamed exactly once -> HBM
// traffic unchanged. Per-4k: 2 global b128 + 4 LDS b128 (48 cyc) + 32 FMA
// (64 cyc) -> FMA-bound. Grid 3125 = N/32 exactly, no bounds checks.
#define XN  32
#define FMA4(acc, xs, wv) \
    acc.x = fmaf(xs, wv.x, acc.x); acc.y = fmaf(xs, wv.y, acc.y); \
    acc.z = fmaf(xs, wv.z, acc.z); acc.w = fmaf(xs, wv.w, acc.w);
__global__ __launch_bounds__(256) void xws_kernel(const float* __restrict__ x,
                                                  const float* __restrict__ W,
                                                  const float* __restrict__ dinv,
                                                  unsigned* __restrict__ xwsh) {
    __shared__ float sW[IN_C * OUT_C];     // 32 KB (only LDS use)
    const int t = threadIdx.x;
    const int n0 = blockIdx.x * XN;
    const float4* W4 = (const float4*)W;
    float4* sW4 = (float4*)sW;
#pragma unroll
    for (int k = 0; k < 8; ++k) sW4[t + k * 256] = W4[t + k * 256];
    __syncthreads();
    const int r  = t >> 4;                 // row 0..15 (and +16)
    const int cq = (t & 15) << 2;          // col quad
    const int na = n0 + r, nb = na + 16;   // always < N_NODES (3125*32 = N)
    const float4* xa = (const float4*)&x[(long long)na * IN_C];
    const float4* xb = (const float4*)&x[(long long)nb * IN_C];
    float4 a0 = make_float4(0.f, 0.f, 0.f, 0.f), a1 = a0;
#pragma unroll 4
    for (int k4 = 0; k4 < IN_C / 4; ++k4) {
        float4 xv0 = xa[k4];               // 16-lane broadcast (same addr)
        float4 xv1 = xb[k4];
        const int k = k4 << 2;
        float4 w0 = *(const float4*)&sW[((k + 0) << 6) + cq];
        float4 w1 = *(const float4*)&sW[((k + 1) << 6) + cq];
        float4 w2 = *(const float4*)&sW[((k + 2) << 6) + cq];
        float4 w3 = *(const float4*)&sW[((k + 3) << 6) + cq];
        FMA4(a0, xv0.x, w0); FMA4(a0, xv0.y, w1); FMA4(a0, xv0.z, w2); FMA4(a0, xv0.w, w3);
        FMA4(a1, xv1.x, w0); FMA4(a1, xv1.y, w1); FMA4(a1, xv1.z, w2); FMA4(a1, xv1.w, w3);
    }
    {
        float di = dinv[na];
        uint2 o = make_uint2(pack_bf16x2(a0.x * di, a0.y * di),
                             pack_bf16x2(a0.z * di, a0.w * di));
        *(uint2*)&xwsh[(long long)na * 32 + ((t & 15) << 1)] = o;
    }
    {
        float di = dinv[nb];
        uint2 o = make_uint2(pack_bf16x2(a1.x * di, a1.y * di),
                             pack_bf16x2(a1.z * di, a1.w * di));
        *(uint2*)&xwsh[(long long)nb * 32 + ((t & 15) << 1)] = o;
    }
}

// ------- pull aggregation + fused epilogue: 2 nodes per wave ---------------
// Single launch (R13-verified; splits cost ~2-3 us/launch in graph gaps)
__global__ __launch_bounds__(256) void aggnode_kernel(
    const int* __restrict__ rowbeg, const int* __restrict__ rowend,
    const int* __restrict__ srcs, const float* __restrict__ dinv,
    const unsigned* __restrict__ xwsh, const float* __restrict__ b,
    const float* __restrict__ Wc, const float* __restrict__ bc,
    float2* __restrict__ p, float2* __restrict__ q) {
    const int lane = threadIdx.x & 63;
    const int hl   = lane & 31;              // lane within node-half
    const int g    = hl >> 3;                // edge slot 0..3
    const int j    = hl & 7;                 // channel octet: ch 8j..8j+7
    const unsigned woff = (unsigned)(j << 2);
    const int node = blockIdx.x * 8 + ((threadIdx.x >> 6) << 1) + (lane >> 5);
    const int beg = rowbeg[node], end = rowend[node];
    const float di = dinv[node];                                   // hoisted
    const uint4 vsl = *(const uint4*)&xwsh[((unsigned)node << 5) + woff]; // hoisted
    float a0=0.f,a1=0.f,a2=0.f,a3=0.f,a4=0.f,a5=0.f,a6=0.f,a7=0.f;
    const int m1 = end - 1;
    for (int i = beg; i < end; i += 16) {
        int e0 = i + g, e1 = e0 + 4, e2 = e0 + 8, e3 = e0 + 12;
        int i0 = min(e0, m1), i1 = min(e1, m1), i2 = min(e2, m1), i3 = min(e3, m1);
        int s0 = srcs[i0], s1 = srcs[i1], s2 = srcs[i2], s3 = srcs[i3];
        float f0 = (e0 < end) ? 1.f : 0.f;
        float f1 = (e1 < end) ? 1.f : 0.f;
        float f2 = (e2 < end) ? 1.f : 0.f;
        float f3 = (e3 < end) ? 1.f : 0.f;
        uint4 v0 = *(const uint4*)&xwsh[((unsigned)s0 << 5) + woff];
        uint4 v1 = *(const uint4*)&xwsh[((unsigned)s1 << 5) + woff];
        uint4 v2 = *(const uint4*)&xwsh[((unsigned)s2 << 5) + woff];
        uint4 v3 = *(const uint4*)&xwsh[((unsigned)s3 << 5) + woff];
        a0 = fmaf(f0, bf_lo(v0.x), a0); a1 = fmaf(f0, bf_hi(v0.x), a1);
        a2 = fmaf(f0, bf_lo(v0.y), a2); a3 = fmaf(f0, bf_hi(v0.y), a3);
        a4 = fmaf(f0, bf_lo(v0.z), a4); a5 = fmaf(f0, bf_hi(v0.z), a5);
        a6 = fmaf(f0, bf_lo(v0.w), a6); a7 = fmaf(f0, bf_hi(v0.w), a7);
        a0 = fmaf(f1, bf_lo(v1.x), a0); a1 = fmaf(f1, bf_hi(v1.x), a1);
        a2 = fmaf(f1, bf_lo(v1.y), a2); a3 = fmaf(f1, bf_hi(v1.y), a3);
        a4 = fmaf(f1, bf_lo(v1.z), a4); a5 = fmaf(f1, bf_hi(v1.z), a5);
        a6 = fmaf(f1, bf_lo(v1.w), a6); a7 = fmaf(f1, bf_hi(v1.w), a7);
        a0 = fmaf(f2, bf_lo(v2.x), a0); a1 = fmaf(f2, bf_hi(v2.x), a1);
        a2 = fmaf(f2, bf_lo(v2.y), a2); a3 = fmaf(f2, bf_hi(v2.y), a3);
        a4 = fmaf(f2, bf_lo(v2.z), a4); a5 = fmaf(f2, bf_hi(v2.z), a5);
        a6 = fmaf(f2, bf_lo(v2.w), a6); a7 = fmaf(f2, bf_hi(v2.w), a7);
        a0 = fmaf(f3, bf_lo(v3.x), a0); a1 = fmaf(f3, bf_hi(v3.x), a1);
        a2 = fmaf(f3, bf_lo(v3.y), a2); a3 = fmaf(f3, bf_hi(v3.y), a3);
        a4 = fmaf(f3, bf_lo(v3.z), a4); a5 = fmaf(f3, bf_hi(v3.z), a5);
        a6 = fmaf(f3, bf_lo(v3.w), a6); a7 = fmaf(f3, bf_hi(v3.w), a7);
    }
    a0 += __shfl_xor(a0, 8); a0 += __shfl_xor(a0, 16);
    a1 += __shfl_xor(a1, 8); a1 += __shfl_xor(a1, 16);
    a2 += __shfl_xor(a2, 8); a2 += __shfl_xor(a2, 16);
    a3 += __shfl_xor(a3, 8); a3 += __shfl_xor(a3, 16);
    a4 += __shfl_xor(a4, 8); a4 += __shfl_xor(a4, 16);
    a5 += __shfl_xor(a5, 8); a5 += __shfl_xor(a5, 16);
    a6 += __shfl_xor(a6, 8); a6 += __shfl_xor(a6, 16);
    a7 += __shfl_xor(a7, 8); a7 += __shfl_xor(a7, 16);
    a0 += bf_lo(vsl.x); a1 += bf_hi(vsl.x);
    a2 += bf_lo(vsl.y); a3 += bf_hi(vsl.y);
    a4 += bf_lo(vsl.z); a5 += bf_hi(vsl.z);
    a6 += bf_lo(vsl.w); a7 += bf_hi(vsl.w);
    float4 bA = ((const float4*)b)[(j << 1)];
    float4 bB = ((const float4*)b)[(j << 1) + 1];
    float h0 = fmaxf(fmaf(di, a0, bA.x), 0.f);
    float h1 = fmaxf(fmaf(di, a1, bA.y), 0.f);
    float h2 = fmaxf(fmaf(di, a2, bA.z), 0.f);
    float h3 = fmaxf(fmaf(di, a3, bA.w), 0.f);
    float h4 = fmaxf(fmaf(di, a4, bB.x), 0.f);
    float h5 = fmaxf(fmaf(di, a5, bB.y), 0.f);
    float h6 = fmaxf(fmaf(di, a6, bB.z), 0.f);
    float h7 = fmaxf(fmaf(di, a7, bB.w), 0.f);
    const float4* WS = (const float4*)Wc;
    const float4* WD = (const float4*)(Wc + 2 * OUT_C);
    float p0, p1, q0, q1;
    {
        float4 w0 = WS[(j << 2)], w1 = WS[(j << 2) + 1];
        float4 w2 = WS[(j << 2) + 2], w3 = WS[(j << 2) + 3];
        p0 = h0 * w0.x + h1 * w0.z + h2 * w1.x + h3 * w1.z
           + h4 * w2.x + h5 * w2.z + h6 * w3.x + h7 * w3.z;
        p1 = h0 * w0.y + h1 * w0.w + h2 * w1.y + h3 * w1.w
           + h4 * w2.y + h5 * w2.w + h6 * w3.y + h7 * w3.w;
    }
    {
        float4 u0 = WD[(j << 2)], u1 = WD[(j << 2) + 1];
        float4 u2 = WD[(j << 2) + 2], u3 = WD[(j << 2) + 3];
        q0 = h0 * u0.x + h1 * u0.z + h2 * u1.x + h3 * u1.z
           + h4 * u2.x + h5 * u2.z + h6 * u3.x + h7 * u3.z;
        q1 = h0 * u0.y + h1 * u0.w + h2 * u1.y + h3 * u1.w
           + h4 * u2.y + h5 * u2.w + h6 * u3.y + h7 * u3.w;
    }
#pragma unroll
    for (int off = 1; off <= 4; off <<= 1) {
        p0 += __shfl_xor(p0, off); p1 += __shfl_xor(p1, off);
        q0 += __shfl_xor(q0, off); q1 += __shfl_xor(q1, off);
    }
    if (hl == 0) {
        p[node] = make_float2(p0 + bc[0], p1 + bc[1]);
        q[node] = make_float2(q0, q1);
    }
}

// ------------ edge outputs: out[e] = p[src] + q[dst], 4 edges/thread --------
__global__ void edge_kernel(const int* __restrict__ ei, const int* __restrict__ nei,
                            const float2* __restrict__ p, const float2* __restrict__ q,
                            float4* __restrict__ out4) {
    int idx = blockIdx.x * blockDim.x + threadIdx.x;
    if (idx >= 2 * N_EDGES / 4) return;
    int e4 = idx * 4;
    const int *S, *D;
    int off;
    if (e4 < N_EDGES) { S = ei;  D = ei  + N_EDGES; off = e4; }
    else              { S = nei; D = nei + N_EDGES; off = e4 - N_EDGES; }
    int4 s4 = *(const int4*)&S[off];
    int4 d4 = *(const int4*)&D[off];
    float2 pa = p[s4.x], qa = q[d4.x];
    float2 pb = p[s4.y], qb = q[d4.y];
    float2 pc = p[s4.z], qc = q[d4.z];
    float2 pd = p[s4.w], qd = q[d4.w];
    out4[idx * 2]     = make_float4(pa.x + qa.x, pa.y + qa.y, pb.x + qb.x, pb.y + qb.y);
    out4[idx * 2 + 1] = make_float4(pc.x + qc.x, pc.y + qc.y, pd.x + qd.x, pd.y + qd.y);
}

extern "C" void kernel_launch(void* const* d_in, const int* in_sizes, int n_in,
                              void* d_out, int out_size, void* d_ws, size_t ws_size,
                              hipStream_t stream) {
    const float* x   = (const float*)d_in[0];   // [N,128]
    const int*   ei  = (const int*)  d_in[1];   // [2,E]
    const int*   nei = (const int*)  d_in[2];   // [2,E]
    const float* W   = (const float*)d_in[3];   // [128,64]
    const float* b   = (const float*)d_in[4];   // [64]
    const float* Wc  = (const float*)d_in[5];   // [128,2]
    const float* bc  = (const float*)d_in[6];   // [2]

    // workspace (ints): end = 3902720 + 196*9216 = 5709056 ints = 22.8 MB
    int*      wsI    = (int*)d_ws;
    float*    dinv   = (float*)wsI;              // N           [0, 100352)
    unsigned* xwsh   = (unsigned*)(wsI + 100352);// N*32 bf16x2 [100352, 3300352)
    float*    p      = (float*)(wsI + 3300352);  // N*2         [3300352, 3501056)
    float*    q      = (float*)(wsI + 3501056);  // N*2         [3501056, 3701760)
    int*      cursor = wsI + 3701760;            // NSB         [3701760, 3702016)
    int*      rowbeg = wsI + 3702016;            // N           [3702016, 3802368)
    int*      rowend = wsI + 3802368;            // N           [3802368, 3902720)
    int*      sbuf   = wsI + 3902720;            // NSB*SCAP

    const int B = 256;
    zero_kernel<<<1, B, 0, stream>>>(cursor);
    sorta_kernel<<<NABLK, 1024, 0, stream>>>(ei, cursor, sbuf);
    sortb_kernel<<<NSB, 1024, 0, stream>>>(cursor, sbuf, dinv, rowbeg, rowend);
    xws_kernel<<<N_NODES / XN, B, 0, stream>>>(x, W, dinv, xwsh);
    aggnode_kernel<<<N_NODES / 8, B, 0, stream>>>(rowbeg, rowend, sbuf, dinv, xwsh,
                                                  b, Wc, bc, (float2*)p, (float2*)q);
    edge_kernel<<<(2 * N_EDGES / 4 + B - 1) / B, B, 0, stream>>>(
        ei, nei, (const float2*)p, (const float2*)q, (float4*)d_out);
}

// Round 16
// 237.257 us; speedup vs baseline: 1.0689x; 1.0329x over previous
//
#include <hip/hip_runtime.h>

#define N_NODES 100000
#define N_EDGES 1600000
#define IN_C    128
#define OUT_C   64

#define SB_NODES 512                               // nodes per super-bucket
#define NSB  ((N_NODES + SB_NODES - 1) / SB_NODES) // 196
#define SCAP 9216                                  // mean 8163, +11 sigma
#define ACHUNK 4096                                // edges per sorta block
#define NABLK ((N_EDGES + ACHUNK - 1) / ACHUNK)    // 391

// ---- bf16x2 helpers ----
__device__ inline unsigned pack_bf16x2(float lo, float hi) {
    unsigned a = __float_as_uint(lo), b2 = __float_as_uint(hi);
    a  += 0x7fff + ((a  >> 16) & 1);               // RNE
    b2 += 0x7fff + ((b2 >> 16) & 1);
    return (a >> 16) | (b2 & 0xffff0000u);
}
__device__ inline float bf_lo(unsigned v) { return __uint_as_float(v << 16); }
__device__ inline float bf_hi(unsigned v) { return __uint_as_float(v & 0xffff0000u); }

// ---------------- zero super-bucket cursors ----------------
__global__ void zero_kernel(int* __restrict__ cursor) {
    int i = blockIdx.x * blockDim.x + threadIdx.x;
    if (i < NSB) cursor[i] = 0;
}

// ------ pass A: partition edges into 196 coarse dst-buckets (512 nodes) -----
// 1024 threads (neutral vs 256t, kept)
__global__ __launch_bounds__(1024) void sorta_kernel(const int* __restrict__ ei,
                                                     int* __restrict__ cursor,
                                                     int* __restrict__ sb) {
    __shared__ int histW[16][NSB];
    __shared__ int base_[NSB];
    __shared__ int cur[NSB];
    const int t = threadIdx.x, w = t >> 6;
    const long long e0 = (long long)blockIdx.x * ACHUNK;
    for (int i = t; i < 16 * NSB; i += 1024) (&histW[0][0])[i] = 0;
    __syncthreads();
    const int* dsts = ei + N_EDGES;
    {
        long long i4 = e0 / 4 + t;                 // 1024 threads x int4 = 4096 edges
        if (i4 * 4 + 3 < N_EDGES) {
            int4 d = *(const int4*)&dsts[i4 * 4];
            atomicAdd(&histW[w][d.x >> 9], 1);
            atomicAdd(&histW[w][d.y >> 9], 1);
            atomicAdd(&histW[w][d.z >> 9], 1);
            atomicAdd(&histW[w][d.w >> 9], 1);
        }
    }
    __syncthreads();
    if (t < NSB) {
        int c = 0;
#pragma unroll
        for (int v = 0; v < 16; ++v) c += histW[v][t];
        base_[t] = c ? atomicAdd(&cursor[t], c) : 0;
        cur[t] = 0;
    }
    __syncthreads();
    {
        long long i4 = e0 / 4 + t;
        if (i4 * 4 + 3 < N_EDGES) {
            int4 s4 = *(const int4*)&ei[i4 * 4];
            int4 d4 = *(const int4*)&dsts[i4 * 4];
            int sv[4] = {s4.x, s4.y, s4.z, s4.w};
            int dv[4] = {d4.x, d4.y, d4.z, d4.w};
#pragma unroll
            for (int j = 0; j < 4; ++j) {
                int bk = dv[j] >> 9;
                int pos = base_[bk] + atomicAdd(&cur[bk], 1);
                if (pos < SCAP)
                    sb[bk * SCAP + pos] = sv[j] * SB_NODES + (dv[j] & (SB_NODES - 1));
            }
        }
    }
}

// ------ pass B: per coarse bucket, LDS counting sort by node -> CSR ---------
// 1024 threads (R11-verified win: -8.1 us vs 256t)
__global__ __launch_bounds__(1024) void sortb_kernel(const int* __restrict__ cursor,
                                                     int* __restrict__ sb,
                                                     float* __restrict__ dinv,
                                                     int* __restrict__ rowbeg,
                                                     int* __restrict__ rowend) {
    __shared__ int hist[SB_NODES];
    __shared__ int pref[SB_NODES + 1];
    __shared__ int cur[SB_NODES];
    __shared__ int sc[SB_NODES];
    __shared__ int sorted[SCAP];                   // 36.9 KB (total ~45 KB)
    const int t = threadIdx.x, b = blockIdx.x;
    if (t < SB_NODES) { hist[t] = 0; cur[t] = 0; }
    __syncthreads();
    int m = cursor[b]; if (m > SCAP) m = SCAP;
    int* bb = sb + b * SCAP;
    for (int i = t; i < m; i += 1024) atomicAdd(&hist[bb[i] & (SB_NODES - 1)], 1);
    __syncthreads();
    if (t < SB_NODES) sc[t] = hist[t];
    __syncthreads();
    for (int off = 1; off < SB_NODES; off <<= 1) { // Hillis-Steele inclusive
        int u = 0;
        if (t < SB_NODES && t >= off) u = sc[t - off];
        __syncthreads();
        if (t < SB_NODES) sc[t] += u;
        __syncthreads();
    }
    if (t < SB_NODES) pref[t] = sc[t] - hist[t];   // exclusive
    if (t == SB_NODES - 1) pref[SB_NODES] = sc[SB_NODES - 1];
    __syncthreads();
    for (int i = t; i < m; i += 1024) {
        int e = bb[i];
        int dl = e & (SB_NODES - 1);
        int pos = pref[dl] + atomicAdd(&cur[dl], 1);
        sorted[pos] = e >> 9;                      // plain src id
    }
    __syncthreads();
    for (int i = t; i < m; i += 1024) bb[i] = sorted[i];  // coalesced writeback
    if (t < SB_NODES) {
        int n = b * SB_NODES + t;
        if (n < N_NODES) {
            rowbeg[n] = b * SCAP + pref[t];
            rowend[n] = b * SCAP + pref[t + 1];
            dinv[n]   = rsqrtf((float)hist[t] + 1.0f);    // +1 self-loop
        }
    }
}

// ------- xws = bf16( dinv[n] * (x @ W) ) : two-phase k-split ---------------
// v3: same staged structure as the 43.5 us original, but k split into two
// 64-wide phases so only half of W (16 KB) and half of x (8.5 KB) are
// resident -> 24.5 KB LDS -> 6 blocks/CU (was 3 at 48.9 KB, occupancy 24%).
// Inner loop, access pattern, and HBM traffic unchanged; accumulators carry
// across phases. Isolates one variable: resident waves for latency hiding.
#define XN   32
#define SXS2 68
#define FMA4(acc, xs, wv) \
    acc.x = fmaf(xs, wv.x, acc.x); acc.y = fmaf(xs, wv.y, acc.y); \
    acc.z = fmaf(xs, wv.z, acc.z); acc.w = fmaf(xs, wv.w, acc.w);
__global__ __launch_bounds__(256) void xws_kernel(const float* __restrict__ x,
                                                  const float* __restrict__ W,
                                                  const float* __restrict__ dinv,
                                                  unsigned* __restrict__ xwsh) {
    __shared__ float sW[64 * OUT_C];       // 16 KB (k-half x 64 cols)
    __shared__ float sx[XN * SXS2];        // 8.5 KB (32 rows x 64 k + pad)
    const int t = threadIdx.x;
    const int n0 = blockIdx.x * XN;
    const int r  = t >> 4;
    const int cq = (t & 15) << 2;
    const int na = n0 + r, nb = na + 16;   // grid exact: always < N_NODES
    float4 a0 = make_float4(0.f, 0.f, 0.f, 0.f), a1 = a0;
#pragma unroll
    for (int ph = 0; ph < 2; ++ph) {
        const int kbase = ph << 6;
        // stage W k-half: 1024 float4, coalesced
#pragma unroll
        for (int u = 0; u < 4; ++u) {
            int fi = t + u * 256;
            int row = fi >> 4, c4 = (fi & 15) << 2;
            *(float4*)&sW[(row << 6) + c4] =
                *(const float4*)&W[((kbase + row) << 6) + c4];
        }
        // stage x k-half: 512 float4, coalesced (16 threads per 256B row-half)
#pragma unroll
        for (int u = 0; u < 2; ++u) {
            int fi = t + u * 256;
            int row = fi >> 4, c4 = (fi & 15) << 2;
            *(float4*)&sx[row * SXS2 + c4] =
                *(const float4*)&x[(long long)(n0 + row) * IN_C + kbase + c4];
        }
        __syncthreads();
#pragma unroll 8
        for (int k = 0; k < 64; ++k) {
            float x0 = sx[r * SXS2 + k];
            float x1 = sx[(r + 16) * SXS2 + k];
            float4 wv = *(const float4*)&sW[(k << 6) + cq];
            FMA4(a0, x0, wv);
            FMA4(a1, x1, wv);
        }
        __syncthreads();
    }
    {
        float di = dinv[na];
        uint2 o = make_uint2(pack_bf16x2(a0.x * di, a0.y * di),
                             pack_bf16x2(a0.z * di, a0.w * di));
        *(uint2*)&xwsh[(long long)na * 32 + ((t & 15) << 1)] = o;
    }
    {
        float di = dinv[nb];
        uint2 o = make_uint2(pack_bf16x2(a1.x * di, a1.y * di),
                             pack_bf16x2(a1.z * di, a1.w * di));
        *(uint2*)&xwsh[(long long)nb * 32 + ((t & 15) << 1)] = o;
    }
}

// ------- pull aggregation + fused epilogue: 2 nodes per wave ---------------
// (R13-verified single launch, latency floor ~49 us)
__global__ __launch_bounds__(256) void aggnode_kernel(
    const int* __restrict__ rowbeg, const int* __restrict__ rowend,
    const int* __restrict__ srcs, const float* __restrict__ dinv,
    const unsigned* __restrict__ xwsh, const float* __restrict__ b,
    const float* __restrict__ Wc, const float* __restrict__ bc,
    float2* __restrict__ p, float2* __restrict__ q) {
    const int lane = threadIdx.x & 63;
    const int hl   = lane & 31;              // lane within node-half
    const int g    = hl >> 3;                // edge slot 0..3
    const int j    = hl & 7;                 // channel octet: ch 8j..8j+7
    const unsigned woff = (unsigned)(j << 2);
    const int node = blockIdx.x * 8 + ((threadIdx.x >> 6) << 1) + (lane >> 5);
    const int beg = rowbeg[node], end = rowend[node];
    const float di = dinv[node];                                   // hoisted
    const uint4 vsl = *(const uint4*)&xwsh[((unsigned)node << 5) + woff]; // hoisted
    float a0=0.f,a1=0.f,a2=0.f,a3=0.f,a4=0.f,a5=0.f,a6=0.f,a7=0.f;
    const int m1 = end - 1;
    for (int i = beg; i < end; i += 16) {
        int e0 = i + g, e1 = e0 + 4, e2 = e0 + 8, e3 = e0 + 12;
        int i0 = min(e0, m1), i1 = min(e1, m1), i2 = min(e2, m1), i3 = min(e3, m1);
        int s0 = srcs[i0], s1 = srcs[i1], s2 = srcs[i2], s3 = srcs[i3];
        float f0 = (e0 < end) ? 1.f : 0.f;
        float f1 = (e1 < end) ? 1.f : 0.f;
        float f2 = (e2 < end) ? 1.f : 0.f;
        float f3 = (e3 < end) ? 1.f : 0.f;
        uint4 v0 = *(const uint4*)&xwsh[((unsigned)s0 << 5) + woff];
        uint4 v1 = *(const uint4*)&xwsh[((unsigned)s1 << 5) + woff];
        uint4 v2 = *(const uint4*)&xwsh[((unsigned)s2 << 5) + woff];
        uint4 v3 = *(const uint4*)&xwsh[((unsigned)s3 << 5) + woff];
        a0 = fmaf(f0, bf_lo(v0.x), a0); a1 = fmaf(f0, bf_hi(v0.x), a1);
        a2 = fmaf(f0, bf_lo(v0.y), a2); a3 = fmaf(f0, bf_hi(v0.y), a3);
        a4 = fmaf(f0, bf_lo(v0.z), a4); a5 = fmaf(f0, bf_hi(v0.z), a5);
        a6 = fmaf(f0, bf_lo(v0.w), a6); a7 = fmaf(f0, bf_hi(v0.w), a7);
        a0 = fmaf(f1, bf_lo(v1.x), a0); a1 = fmaf(f1, bf_hi(v1.x), a1);
        a2 = fmaf(f1, bf_lo(v1.y), a2); a3 = fmaf(f1, bf_hi(v1.y), a3);
        a4 = fmaf(f1, bf_lo(v1.z), a4); a5 = fmaf(f1, bf_hi(v1.z), a5);
        a6 = fmaf(f1, bf_lo(v1.w), a6); a7 = fmaf(f1, bf_hi(v1.w), a7);
        a0 = fmaf(f2, bf_lo(v2.x), a0); a1 = fmaf(f2, bf_hi(v2.x), a1);
        a2 = fmaf(f2, bf_lo(v2.y), a2); a3 = fmaf(f2, bf_hi(v2.y), a3);
        a4 = fmaf(f2, bf_lo(v2.z), a4); a5 = fmaf(f2, bf_hi(v2.z), a5);
        a6 = fmaf(f2, bf_lo(v2.w), a6); a7 = fmaf(f2, bf_hi(v2.w), a7);
        a0 = fmaf(f3, bf_lo(v3.x), a0); a1 = fmaf(f3, bf_hi(v3.x), a1);
        a2 = fmaf(f3, bf_lo(v3.y), a2); a3 = fmaf(f3, bf_hi(v3.y), a3);
        a4 = fmaf(f3, bf_lo(v3.z), a4); a5 = fmaf(f3, bf_hi(v3.z), a5);
        a6 = fmaf(f3, bf_lo(v3.w), a6); a7 = fmaf(f3, bf_hi(v3.w), a7);
    }
    a0 += __shfl_xor(a0, 8); a0 += __shfl_xor(a0, 16);
    a1 += __shfl_xor(a1, 8); a1 += __shfl_xor(a1, 16);
    a2 += __shfl_xor(a2, 8); a2 += __shfl_xor(a2, 16);
    a3 += __shfl_xor(a3, 8); a3 += __shfl_xor(a3, 16);
    a4 += __shfl_xor(a4, 8); a4 += __shfl_xor(a4, 16);
    a5 += __shfl_xor(a5, 8); a5 += __shfl_xor(a5, 16);
    a6 += __shfl_xor(a6, 8); a6 += __shfl_xor(a6, 16);
    a7 += __shfl_xor(a7, 8); a7 += __shfl_xor(a7, 16);
    a0 += bf_lo(vsl.x); a1 += bf_hi(vsl.x);
    a2 += bf_lo(vsl.y); a3 += bf_hi(vsl.y);
    a4 += bf_lo(vsl.z); a5 += bf_hi(vsl.z);
    a6 += bf_lo(vsl.w); a7 += bf_hi(vsl.w);
    float4 bA = ((const float4*)b)[(j << 1)];
    float4 bB = ((const float4*)b)[(j << 1) + 1];
    float h0 = fmaxf(fmaf(di, a0, bA.x), 0.f);
    float h1 = fmaxf(fmaf(di, a1, bA.y), 0.f);
    float h2 = fmaxf(fmaf(di, a2, bA.z), 0.f);
    float h3 = fmaxf(fmaf(di, a3, bA.w), 0.f);
    float h4 = fmaxf(fmaf(di, a4, bB.x), 0.f);
    float h5 = fmaxf(fmaf(di, a5, bB.y), 0.f);
    float h6 = fmaxf(fmaf(di, a6, bB.z), 0.f);
    float h7 = fmaxf(fmaf(di, a7, bB.w), 0.f);
    const float4* WS = (const float4*)Wc;
    const float4* WD = (const float4*)(Wc + 2 * OUT_C);
    float p0, p1, q0, q1;
    {
        float4 w0 = WS[(j << 2)], w1 = WS[(j << 2) + 1];
        float4 w2 = WS[(j << 2) + 2], w3 = WS[(j << 2) + 3];
        p0 = h0 * w0.x + h1 * w0.z + h2 * w1.x + h3 * w1.z
           + h4 * w2.x + h5 * w2.z + h6 * w3.x + h7 * w3.z;
        p1 = h0 * w0.y + h1 * w0.w + h2 * w1.y + h3 * w1.w
           + h4 * w2.y + h5 * w2.w + h6 * w3.y + h7 * w3.w;
    }
    {
        float4 u0 = WD[(j << 2)], u1 = WD[(j << 2) + 1];
        float4 u2 = WD[(j << 2) + 2], u3 = WD[(j << 2) + 3];
        q0 = h0 * u0.x + h1 * u0.z + h2 * u1.x + h3 * u1.z
           + h4 * u2.x + h5 * u2.z + h6 * u3.x + h7 * u3.z;
        q1 = h0 * u0.y + h1 * u0.w + h2 * u1.y + h3 * u1.w
           + h4 * u2.y + h5 * u2.w + h6 * u3.y + h7 * u3.w;
    }
#pragma unroll
    for (int off = 1; off <= 4; off <<= 1) {
        p0 += __shfl_xor(p0, off); p1 += __shfl_xor(p1, off);
        q0 += __shfl_xor(q0, off); q1 += __shfl_xor(q1, off);
    }
    if (hl == 0) {
        p[node] = make_float2(p0 + bc[0], p1 + bc[1]);
        q[node] = make_float2(q0, q1);
    }
}

// ------------ edge outputs: out[e] = p[src] + q[dst], 4 edges/thread --------
__global__ void edge_kernel(const int* __restrict__ ei, const int* __restrict__ nei,
                            const float2* __restrict__ p, const float2* __restrict__ q,
                            float4* __restrict__ out4) {
    int idx = blockIdx.x * blockDim.x + threadIdx.x;
    if (idx >= 2 * N_EDGES / 4) return;
    int e4 = idx * 4;
    const int *S, *D;
    int off;
    if (e4 < N_EDGES) { S = ei;  D = ei  + N_EDGES; off = e4; }
    else              { S = nei; D = nei + N_EDGES; off = e4 - N_EDGES; }
    int4 s4 = *(const int4*)&S[off];
    int4 d4 = *(const int4*)&D[off];
    float2 pa = p[s4.x], qa = q[d4.x];
    float2 pb = p[s4.y], qb = q[d4.y];
    float2 pc = p[s4.z], qc = q[d4.z];
    float2 pd = p[s4.w], qd = q[d4.w];
    out4[idx * 2]     = make_float4(pa.x + qa.x, pa.y + qa.y, pb.x + qb.x, pb.y + qb.y);
    out4[idx * 2 + 1] = make_float4(pc.x + qc.x, pc.y + qc.y, pd.x + qd.x, pd.y + qd.y);
}

extern "C" void kernel_launch(void* const* d_in, const int* in_sizes, int n_in,
                              void* d_out, int out_size, void* d_ws, size_t ws_size,
                              hipStream_t stream) {
    const float* x   = (const float*)d_in[0];   // [N,128]
    const int*   ei  = (const int*)  d_in[1];   // [2,E]
    const int*   nei = (const int*)  d_in[2];   // [2,E]
    const float* W   = (const float*)d_in[3];   // [128,64]
    const float* b   = (const float*)d_in[4];   // [64]
    const float* Wc  = (const float*)d_in[5];   // [128,2]
    const float* bc  = (const float*)d_in[6];   // [2]

    // workspace (ints): end = 3902720 + 196*9216 = 5709056 ints = 22.8 MB
    int*      wsI    = (int*)d_ws;
    float*    dinv   = (float*)wsI;              // N           [0, 100352)
    unsigned* xwsh   = (unsigned*)(wsI + 100352);// N*32 bf16x2 [100352, 3300352)
    float*    p      = (float*)(wsI + 3300352);  // N*2         [3300352, 3501056)
    float*    q      = (float*)(wsI + 3501056);  // N*2         [3501056, 3701760)
    int*      cursor = wsI + 3701760;            // NSB         [3701760, 3702016)
    int*      rowbeg = wsI + 3702016;            // N           [3702016, 3802368)
    int*      rowend = wsI + 3802368;            // N           [3802368, 3902720)
    int*      sbuf   = wsI + 3902720;            // NSB*SCAP

    const int B = 256;
    zero_kernel<<<1, B, 0, stream>>>(cursor);
    sorta_kernel<<<NABLK, 1024, 0, stream>>>(ei, cursor, sbuf);
    sortb_kernel<<<NSB, 1024, 0, stream>>>(cursor, sbuf, dinv, rowbeg, rowend);
    xws_kernel<<<N_NODES / XN, B, 0, stream>>>(x, W, dinv, xwsh);
    aggnode_kernel<<<N_NODES / 8, B, 0, stream>>>(rowbeg, rowend, sbuf, dinv, xwsh,
                                                  b, Wc, bc, (float2*)p, (float2*)q);
    edge_kernel<<<(2 * N_EDGES / 4 + B - 1) / B, B, 0, stream>>>(
        ei, nei, (const float2*)p, (const float2*)q, (float4*)d_out);
}

// Round 17
// 234.088 us; speedup vs baseline: 1.0833x; 1.0135x over previous
//
#include <hip/hip_runtime.h>

#define N_NODES 100000
#define N_EDGES 1600000
#define IN_C    128
#define OUT_C   64

#define SB_NODES 512                               // nodes per super-bucket
#define NSB  ((N_NODES + SB_NODES - 1) / SB_NODES) // 196
#define SCAP 9216                                  // mean 8163, +11 sigma
#define ACHUNK 4096                                // edges per sorta block
#define NABLK ((N_EDGES + ACHUNK - 1) / ACHUNK)    // 391

// ---- bf16x2 helpers ----
__device__ inline unsigned pack_bf16x2(float lo, float hi) {
    unsigned a = __float_as_uint(lo), b2 = __float_as_uint(hi);
    a  += 0x7fff + ((a  >> 16) & 1);               // RNE
    b2 += 0x7fff + ((b2 >> 16) & 1);
    return (a >> 16) | (b2 & 0xffff0000u);
}
__device__ inline float bf_lo(unsigned v) { return __uint_as_float(v << 16); }
__device__ inline float bf_hi(unsigned v) { return __uint_as_float(v & 0xffff0000u); }

// ------ pass A: partition edges into 196 coarse dst-buckets (512 nodes) -----
// 1024 threads (neutral vs 256t, kept)
__global__ __launch_bounds__(1024) void sorta_kernel(const int* __restrict__ ei,
                                                     int* __restrict__ cursor,
                                                     int* __restrict__ sb) {
    __shared__ int histW[16][NSB];
    __shared__ int base_[NSB];
    __shared__ int cur[NSB];
    const int t = threadIdx.x, w = t >> 6;
    const long long e0 = (long long)blockIdx.x * ACHUNK;
    for (int i = t; i < 16 * NSB; i += 1024) (&histW[0][0])[i] = 0;
    __syncthreads();
    const int* dsts = ei + N_EDGES;
    {
        long long i4 = e0 / 4 + t;                 // 1024 threads x int4 = 4096 edges
        if (i4 * 4 + 3 < N_EDGES) {
            int4 d = *(const int4*)&dsts[i4 * 4];
            atomicAdd(&histW[w][d.x >> 9], 1);
            atomicAdd(&histW[w][d.y >> 9], 1);
            atomicAdd(&histW[w][d.z >> 9], 1);
            atomicAdd(&histW[w][d.w >> 9], 1);
        }
    }
    __syncthreads();
    if (t < NSB) {
        int c = 0;
#pragma unroll
        for (int v = 0; v < 16; ++v) c += histW[v][t];
        base_[t] = c ? atomicAdd(&cursor[t], c) : 0;
        cur[t] = 0;
    }
    __syncthreads();
    {
        long long i4 = e0 / 4 + t;
        if (i4 * 4 + 3 < N_EDGES) {
            int4 s4 = *(const int4*)&ei[i4 * 4];
            int4 d4 = *(const int4*)&dsts[i4 * 4];
            int sv[4] = {s4.x, s4.y, s4.z, s4.w};
            int dv[4] = {d4.x, d4.y, d4.z, d4.w};
#pragma unroll
            for (int j = 0; j < 4; ++j) {
                int bk = dv[j] >> 9;
                int pos = base_[bk] + atomicAdd(&cur[bk], 1);
                if (pos < SCAP)
                    sb[bk * SCAP + pos] = sv[j] * SB_NODES + (dv[j] & (SB_NODES - 1));
            }
        }
    }
}

// ------ pass B: per coarse bucket, LDS counting sort by node -> CSR ---------
// 1024 threads (R11-verified win: -8.1 us vs 256t)
__global__ __launch_bounds__(1024) void sortb_kernel(const int* __restrict__ cursor,
                                                     int* __restrict__ sb,
                                                     float* __restrict__ dinv,
                                                     int* __restrict__ rowbeg,
                                                     int* __restrict__ rowend) {
    __shared__ int hist[SB_NODES];
    __shared__ int pref[SB_NODES + 1];
    __shared__ int cur[SB_NODES];
    __shared__ int sc[SB_NODES];
    __shared__ int sorted[SCAP];                   // 36.9 KB (total ~45 KB)
    const int t = threadIdx.x, b = blockIdx.x;
    if (t < SB_NODES) { hist[t] = 0; cur[t] = 0; }
    __syncthreads();
    int m = cursor[b]; if (m > SCAP) m = SCAP;
    int* bb = sb + b * SCAP;
    for (int i = t; i < m; i += 1024) atomicAdd(&hist[bb[i] & (SB_NODES - 1)], 1);
    __syncthreads();
    if (t < SB_NODES) sc[t] = hist[t];
    __syncthreads();
    for (int off = 1; off < SB_NODES; off <<= 1) { // Hillis-Steele inclusive
        int u = 0;
        if (t < SB_NODES && t >= off) u = sc[t - off];
        __syncthreads();
        if (t < SB_NODES) sc[t] += u;
        __syncthreads();
    }
    if (t < SB_NODES) pref[t] = sc[t] - hist[t];   // exclusive
    if (t == SB_NODES - 1) pref[SB_NODES] = sc[SB_NODES - 1];
    __syncthreads();
    for (int i = t; i < m; i += 1024) {
        int e = bb[i];
        int dl = e & (SB_NODES - 1);
        int pos = pref[dl] + atomicAdd(&cur[dl], 1);
        sorted[pos] = e >> 9;                      // plain src id
    }
    __syncthreads();
    for (int i = t; i < m; i += 1024) bb[i] = sorted[i];  // coalesced writeback
    if (t < SB_NODES) {
        int n = b * SB_NODES + t;
        if (n < N_NODES) {
            rowbeg[n] = b * SCAP + pref[t];
            rowend[n] = b * SCAP + pref[t + 1];
            dinv[n]   = rsqrtf((float)hist[t] + 1.0f);    // +1 self-loop
        }
    }
}

// ------- xws = bf16( dinv[n] * (x @ W) ) : two-phase k-split ---------------
// (R15-verified: 24.5 KB LDS -> 6 blocks/CU, total -1.8 us vs 48.9 KB)
#define XN   32
#define SXS2 68
#define FMA4(acc, xs, wv) \
    acc.x = fmaf(xs, wv.x, acc.x); acc.y = fmaf(xs, wv.y, acc.y); \
    acc.z = fmaf(xs, wv.z, acc.z); acc.w = fmaf(xs, wv.w, acc.w);
__global__ __launch_bounds__(256) void xws_kernel(const float* __restrict__ x,
                                                  const float* __restrict__ W,
                                                  const float* __restrict__ dinv,
                                                  unsigned* __restrict__ xwsh) {
    __shared__ float sW[64 * OUT_C];       // 16 KB (k-half x 64 cols)
    __shared__ float sx[XN * SXS2];        // 8.5 KB (32 rows x 64 k + pad)
    const int t = threadIdx.x;
    const int n0 = blockIdx.x * XN;
    const int r  = t >> 4;
    const int cq = (t & 15) << 2;
    const int na = n0 + r, nb = na + 16;   // grid exact: always < N_NODES
    float4 a0 = make_float4(0.f, 0.f, 0.f, 0.f), a1 = a0;
#pragma unroll
    for (int ph = 0; ph < 2; ++ph) {
        const int kbase = ph << 6;
#pragma unroll
        for (int u = 0; u < 4; ++u) {
            int fi = t + u * 256;
            int row = fi >> 4, c4 = (fi & 15) << 2;
            *(float4*)&sW[(row << 6) + c4] =
                *(const float4*)&W[((kbase + row) << 6) + c4];
        }
#pragma unroll
        for (int u = 0; u < 2; ++u) {
            int fi = t + u * 256;
            int row = fi >> 4, c4 = (fi & 15) << 2;
            *(float4*)&sx[row * SXS2 + c4] =
                *(const float4*)&x[(long long)(n0 + row) * IN_C + kbase + c4];
        }
        __syncthreads();
#pragma unroll 8
        for (int k = 0; k < 64; ++k) {
            float x0 = sx[r * SXS2 + k];
            float x1 = sx[(r + 16) * SXS2 + k];
            float4 wv = *(const float4*)&sW[(k << 6) + cq];
            FMA4(a0, x0, wv);
            FMA4(a1, x1, wv);
        }
        __syncthreads();
    }
    {
        float di = dinv[na];
        uint2 o = make_uint2(pack_bf16x2(a0.x * di, a0.y * di),
                             pack_bf16x2(a0.z * di, a0.w * di));
        *(uint2*)&xwsh[(long long)na * 32 + ((t & 15) << 1)] = o;
    }
    {
        float di = dinv[nb];
        uint2 o = make_uint2(pack_bf16x2(a1.x * di, a1.y * di),
                             pack_bf16x2(a1.z * di, a1.w * di));
        *(uint2*)&xwsh[(long long)nb * 32 + ((t & 15) << 1)] = o;
    }
}

// ------- pull aggregation + fused epilogue: 2 nodes per wave ---------------
// (latency floor ~48 us, 4 variants converged)
__global__ __launch_bounds__(256) void aggnode_kernel(
    const int* __restrict__ rowbeg, const int* __restrict__ rowend,
    const int* __restrict__ srcs, const float* __restrict__ dinv,
    const unsigned* __restrict__ xwsh, const float* __restrict__ b,
    const float* __restrict__ Wc, const float* __restrict__ bc,
    float2* __restrict__ p, float2* __restrict__ q) {
    const int lane = threadIdx.x & 63;
    const int hl   = lane & 31;              // lane within node-half
    const int g    = hl >> 3;                // edge slot 0..3
    const int j    = hl & 7;                 // channel octet: ch 8j..8j+7
    const unsigned woff = (unsigned)(j << 2);
    const int node = blockIdx.x * 8 + ((threadIdx.x >> 6) << 1) + (lane >> 5);
    const int beg = rowbeg[node], end = rowend[node];
    const float di = dinv[node];                                   // hoisted
    const uint4 vsl = *(const uint4*)&xwsh[((unsigned)node << 5) + woff]; // hoisted
    float a0=0.f,a1=0.f,a2=0.f,a3=0.f,a4=0.f,a5=0.f,a6=0.f,a7=0.f;
    const int m1 = end - 1;
    for (int i = beg; i < end; i += 16) {
        int e0 = i + g, e1 = e0 + 4, e2 = e0 + 8, e3 = e0 + 12;
        int i0 = min(e0, m1), i1 = min(e1, m1), i2 = min(e2, m1), i3 = min(e3, m1);
        int s0 = srcs[i0], s1 = srcs[i1], s2 = srcs[i2], s3 = srcs[i3];
        float f0 = (e0 < end) ? 1.f : 0.f;
        float f1 = (e1 < end) ? 1.f : 0.f;
        float f2 = (e2 < end) ? 1.f : 0.f;
        float f3 = (e3 < end) ? 1.f : 0.f;
        uint4 v0 = *(const uint4*)&xwsh[((unsigned)s0 << 5) + woff];
        uint4 v1 = *(const uint4*)&xwsh[((unsigned)s1 << 5) + woff];
        uint4 v2 = *(const uint4*)&xwsh[((unsigned)s2 << 5) + woff];
        uint4 v3 = *(const uint4*)&xwsh[((unsigned)s3 << 5) + woff];
        a0 = fmaf(f0, bf_lo(v0.x), a0); a1 = fmaf(f0, bf_hi(v0.x), a1);
        a2 = fmaf(f0, bf_lo(v0.y), a2); a3 = fmaf(f0, bf_hi(v0.y), a3);
        a4 = fmaf(f0, bf_lo(v0.z), a4); a5 = fmaf(f0, bf_hi(v0.z), a5);
        a6 = fmaf(f0, bf_lo(v0.w), a6); a7 = fmaf(f0, bf_hi(v0.w), a7);
        a0 = fmaf(f1, bf_lo(v1.x), a0); a1 = fmaf(f1, bf_hi(v1.x), a1);
        a2 = fmaf(f1, bf_lo(v1.y), a2); a3 = fmaf(f1, bf_hi(v1.y), a3);
        a4 = fmaf(f1, bf_lo(v1.z), a4); a5 = fmaf(f1, bf_hi(v1.z), a5);
        a6 = fmaf(f1, bf_lo(v1.w), a6); a7 = fmaf(f1, bf_hi(v1.w), a7);
        a0 = fmaf(f2, bf_lo(v2.x), a0); a1 = fmaf(f2, bf_hi(v2.x), a1);
        a2 = fmaf(f2, bf_lo(v2.y), a2); a3 = fmaf(f2, bf_hi(v2.y), a3);
        a4 = fmaf(f2, bf_lo(v2.z), a4); a5 = fmaf(f2, bf_hi(v2.z), a5);
        a6 = fmaf(f2, bf_lo(v2.w), a6); a7 = fmaf(f2, bf_hi(v2.w), a7);
        a0 = fmaf(f3, bf_lo(v3.x), a0); a1 = fmaf(f3, bf_hi(v3.x), a1);
        a2 = fmaf(f3, bf_lo(v3.y), a2); a3 = fmaf(f3, bf_hi(v3.y), a3);
        a4 = fmaf(f3, bf_lo(v3.z), a4); a5 = fmaf(f3, bf_hi(v3.z), a5);
        a6 = fmaf(f3, bf_lo(v3.w), a6); a7 = fmaf(f3, bf_hi(v3.w), a7);
    }
    a0 += __shfl_xor(a0, 8); a0 += __shfl_xor(a0, 16);
    a1 += __shfl_xor(a1, 8); a1 += __shfl_xor(a1, 16);
    a2 += __shfl_xor(a2, 8); a2 += __shfl_xor(a2, 16);
    a3 += __shfl_xor(a3, 8); a3 += __shfl_xor(a3, 16);
    a4 += __shfl_xor(a4, 8); a4 += __shfl_xor(a4, 16);
    a5 += __shfl_xor(a5, 8); a5 += __shfl_xor(a5, 16);
    a6 += __shfl_xor(a6, 8); a6 += __shfl_xor(a6, 16);
    a7 += __shfl_xor(a7, 8); a7 += __shfl_xor(a7, 16);
    a0 += bf_lo(vsl.x); a1 += bf_hi(vsl.x);
    a2 += bf_lo(vsl.y); a3 += bf_hi(vsl.y);
    a4 += bf_lo(vsl.z); a5 += bf_hi(vsl.z);
    a6 += bf_lo(vsl.w); a7 += bf_hi(vsl.w);
    float4 bA = ((const float4*)b)[(j << 1)];
    float4 bB = ((const float4*)b)[(j << 1) + 1];
    float h0 = fmaxf(fmaf(di, a0, bA.x), 0.f);
    float h1 = fmaxf(fmaf(di, a1, bA.y), 0.f);
    float h2 = fmaxf(fmaf(di, a2, bA.z), 0.f);
    float h3 = fmaxf(fmaf(di, a3, bA.w), 0.f);
    float h4 = fmaxf(fmaf(di, a4, bB.x), 0.f);
    float h5 = fmaxf(fmaf(di, a5, bB.y), 0.f);
    float h6 = fmaxf(fmaf(di, a6, bB.z), 0.f);
    float h7 = fmaxf(fmaf(di, a7, bB.w), 0.f);
    const float4* WS = (const float4*)Wc;
    const float4* WD = (const float4*)(Wc + 2 * OUT_C);
    float p0, p1, q0, q1;
    {
        float4 w0 = WS[(j << 2)], w1 = WS[(j << 2) + 1];
        float4 w2 = WS[(j << 2) + 2], w3 = WS[(j << 2) + 3];
        p0 = h0 * w0.x + h1 * w0.z + h2 * w1.x + h3 * w1.z
           + h4 * w2.x + h5 * w2.z + h6 * w3.x + h7 * w3.z;
        p1 = h0 * w0.y + h1 * w0.w + h2 * w1.y + h3 * w1.w
           + h4 * w2.y + h5 * w2.w + h6 * w3.y + h7 * w3.w;
    }
    {
        float4 u0 = WD[(j << 2)], u1 = WD[(j << 2) + 1];
        float4 u2 = WD[(j << 2) + 2], u3 = WD[(j << 2) + 3];
        q0 = h0 * u0.x + h1 * u0.z + h2 * u1.x + h3 * u1.z
           + h4 * u2.x + h5 * u2.z + h6 * u3.x + h7 * u3.z;
        q1 = h0 * u0.y + h1 * u0.w + h2 * u1.y + h3 * u1.w
           + h4 * u2.y + h5 * u2.w + h6 * u3.y + h7 * u3.w;
    }
#pragma unroll
    for (int off = 1; off <= 4; off <<= 1) {
        p0 += __shfl_xor(p0, off); p1 += __shfl_xor(p1, off);
        q0 += __shfl_xor(q0, off); q1 += __shfl_xor(q1, off);
    }
    if (hl == 0) {
        p[node] = make_float2(p0 + bc[0], p1 + bc[1]);
        q[node] = make_float2(q0, q1);
    }
}

// ------------ edge outputs: out[e] = p[src] + q[dst], 2 edges/thread --------
// Latency-bound (VALUBusy 1.6% @4/t); measured trend 16/t > 8/t > 4/t in
// cost -> extrapolate: 2/t doubles resident blocks (6250, ~24/CU) for more
// outstanding-request TLP. Output = exactly one float4/thread.
__global__ __launch_bounds__(256) void edge_kernel(
    const int* __restrict__ ei, const int* __restrict__ nei,
    const float2* __restrict__ p, const float2* __restrict__ q,
    float4* __restrict__ out4) {
    int idx = blockIdx.x * blockDim.x + threadIdx.x;
    if (idx >= N_EDGES) return;                    // 2*N_EDGES/2 threads
    int e2 = idx * 2;
    const int *S, *D;
    int off;
    if (e2 < N_EDGES) { S = ei;  D = ei  + N_EDGES; off = e2; }
    else              { S = nei; D = nei + N_EDGES; off = e2 - N_EDGES; }
    int2 s2 = *(const int2*)&S[off];
    int2 d2 = *(const int2*)&D[off];
    float2 pa = p[s2.x], qa = q[d2.x];
    float2 pb = p[s2.y], qb = q[d2.y];
    out4[idx] = make_float4(pa.x + qa.x, pa.y + qa.y, pb.x + qb.x, pb.y + qb.y);
}

extern "C" void kernel_launch(void* const* d_in, const int* in_sizes, int n_in,
                              void* d_out, int out_size, void* d_ws, size_t ws_size,
                              hipStream_t stream) {
    const float* x   = (const float*)d_in[0];   // [N,128]
    const int*   ei  = (const int*)  d_in[1];   // [2,E]
    const int*   nei = (const int*)  d_in[2];   // [2,E]
    const float* W   = (const float*)d_in[3];   // [128,64]
    const float* b   = (const float*)d_in[4];   // [64]
    const float* Wc  = (const float*)d_in[5];   // [128,2]
    const float* bc  = (const float*)d_in[6];   // [2]

    // workspace (ints): end = 3902720 + 196*9216 = 5709056 ints = 22.8 MB
    int*      wsI    = (int*)d_ws;
    float*    dinv   = (float*)wsI;              // N           [0, 100352)
    unsigned* xwsh   = (unsigned*)(wsI + 100352);// N*32 bf16x2 [100352, 3300352)
    float*    p      = (float*)(wsI + 3300352);  // N*2         [3300352, 3501056)
    float*    q      = (float*)(wsI + 3501056);  // N*2         [3501056, 3701760)
    int*      cursor = wsI + 3701760;            // NSB         [3701760, 3702016)
    int*      rowbeg = wsI + 3702016;            // N           [3702016, 3802368)
    int*      rowend = wsI + 3802368;            // N           [3802368, 3902720)
    int*      sbuf   = wsI + 3902720;            // NSB*SCAP

    const int B = 256;
    hipMemsetAsync(cursor, 0, NSB * sizeof(int), stream);   // replaces zero_kernel
    sorta_kernel<<<NABLK, 1024, 0, stream>>>(ei, cursor, sbuf);
    sortb_kernel<<<NSB, 1024, 0, stream>>>(cursor, sbuf, dinv, rowbeg, rowend);
    xws_kernel<<<N_NODES / XN, B, 0, stream>>>(x, W, dinv, xwsh);
    aggnode_kernel<<<N_NODES / 8, B, 0, stream>>>(rowbeg, rowend, sbuf, dinv, xwsh,
                                                  b, Wc, bc, (float2*)p, (float2*)q);
    edge_kernel<<<(N_EDGES + B - 1) / B, B, 0, stream>>>(
        ei, nei, (const float2*)p, (const float2*)q, (float4*)d_out);
}

// Round 18
// 233.147 us; speedup vs baseline: 1.0877x; 1.0040x over previous
//
#include <hip/hip_runtime.h>

#define N_NODES 100000
#define N_EDGES 1600000
#define IN_C    128
#define OUT_C   64

#define SB_NODES 256                               // nodes per super-bucket
#define NSB  ((N_NODES + SB_NODES - 1) / SB_NODES) // 391
#define SCAP 4608                                  // mean 4096 + ~8 sigma
#define ACHUNK 4096                                // edges per sorta block
#define NABLK ((N_EDGES + ACHUNK - 1) / ACHUNK)    // 391

// ---- bf16x2 helpers ----
__device__ inline unsigned pack_bf16x2(float lo, float hi) {
    unsigned a = __float_as_uint(lo), b2 = __float_as_uint(hi);
    a  += 0x7fff + ((a  >> 16) & 1);               // RNE
    b2 += 0x7fff + ((b2 >> 16) & 1);
    return (a >> 16) | (b2 & 0xffff0000u);
}
__device__ inline float bf_lo(unsigned v) { return __uint_as_float(v << 16); }
__device__ inline float bf_hi(unsigned v) { return __uint_as_float(v & 0xffff0000u); }

// ------ pass A: partition edges into 391 dst-buckets (256 nodes each) -------
// entry = src*256 + (dst & 255); bucket = dst >> 8
__global__ __launch_bounds__(1024) void sorta_kernel(const int* __restrict__ ei,
                                                     int* __restrict__ cursor,
                                                     int* __restrict__ sb) {
    __shared__ int histW[16][NSB];                 // 25 KB
    __shared__ int base_[NSB];
    __shared__ int cur[NSB];
    const int t = threadIdx.x, w = t >> 6;
    const long long e0 = (long long)blockIdx.x * ACHUNK;
    for (int i = t; i < 16 * NSB; i += 1024) (&histW[0][0])[i] = 0;
    __syncthreads();
    const int* dsts = ei + N_EDGES;
    {
        long long i4 = e0 / 4 + t;                 // 1024 threads x int4 = 4096 edges
        if (i4 * 4 + 3 < N_EDGES) {
            int4 d = *(const int4*)&dsts[i4 * 4];
            atomicAdd(&histW[w][d.x >> 8], 1);
            atomicAdd(&histW[w][d.y >> 8], 1);
            atomicAdd(&histW[w][d.z >> 8], 1);
            atomicAdd(&histW[w][d.w >> 8], 1);
        }
    }
    __syncthreads();
    for (int i = t; i < NSB; i += 1024) {
        int c = 0;
#pragma unroll
        for (int v = 0; v < 16; ++v) c += histW[v][i];
        base_[i] = c ? atomicAdd(&cursor[i], c) : 0;
        cur[i] = 0;
    }
    __syncthreads();
    {
        long long i4 = e0 / 4 + t;
        if (i4 * 4 + 3 < N_EDGES) {
            int4 s4 = *(const int4*)&ei[i4 * 4];
            int4 d4 = *(const int4*)&dsts[i4 * 4];
            int sv[4] = {s4.x, s4.y, s4.z, s4.w};
            int dv[4] = {d4.x, d4.y, d4.z, d4.w};
#pragma unroll
            for (int j = 0; j < 4; ++j) {
                int bk = dv[j] >> 8;
                int pos = base_[bk] + atomicAdd(&cur[bk], 1);
                if (pos < SCAP)
                    sb[bk * SCAP + pos] = sv[j] * SB_NODES + (dv[j] & (SB_NODES - 1));
            }
        }
    }
}

// ------ pass B: per bucket, LDS counting sort by node -> CSR ---------------
// 391 blocks (was 196: <1/CU, 60 CUs idle) x half the per-block edges.
// LDS ~23 KB.
__global__ __launch_bounds__(1024) void sortb_kernel(const int* __restrict__ cursor,
                                                     int* __restrict__ sb,
                                                     float* __restrict__ dinv,
                                                     int* __restrict__ rowbeg,
                                                     int* __restrict__ rowend) {
    __shared__ int hist[SB_NODES];
    __shared__ int pref[SB_NODES + 1];
    __shared__ int cur[SB_NODES];
    __shared__ int sc[SB_NODES];
    __shared__ int sorted[SCAP];                   // 18 KB
    const int t = threadIdx.x, b = blockIdx.x;
    if (t < SB_NODES) { hist[t] = 0; cur[t] = 0; }
    __syncthreads();
    int m = cursor[b]; if (m > SCAP) m = SCAP;
    int* bb = sb + b * SCAP;
    for (int i = t; i < m; i += 1024) atomicAdd(&hist[bb[i] & (SB_NODES - 1)], 1);
    __syncthreads();
    if (t < SB_NODES) sc[t] = hist[t];
    __syncthreads();
    for (int off = 1; off < SB_NODES; off <<= 1) { // Hillis-Steele inclusive
        int u = 0;
        if (t < SB_NODES && t >= off) u = sc[t - off];
        __syncthreads();
        if (t < SB_NODES) sc[t] += u;
        __syncthreads();
    }
    if (t < SB_NODES) pref[t] = sc[t] - hist[t];   // exclusive
    if (t == SB_NODES - 1) pref[SB_NODES] = sc[SB_NODES - 1];
    __syncthreads();
    for (int i = t; i < m; i += 1024) {
        int e = bb[i];
        int dl = e & (SB_NODES - 1);
        int pos = pref[dl] + atomicAdd(&cur[dl], 1);
        sorted[pos] = e >> 8;                      // plain src id
    }
    __syncthreads();
    for (int i = t; i < m; i += 1024) bb[i] = sorted[i];  // coalesced writeback
    if (t < SB_NODES) {
        int n = b * SB_NODES + t;
        if (n < N_NODES) {
            rowbeg[n] = b * SCAP + pref[t];
            rowend[n] = b * SCAP + pref[t + 1];
            dinv[n]   = rsqrtf((float)hist[t] + 1.0f);    // +1 self-loop
        }
    }
}

// ------- xws = bf16( dinv[n] * (x @ W) ) : two-phase k-split ---------------
// (R15-verified: 24.5 KB LDS -> 6 blocks/CU)
#define XN   32
#define SXS2 68
#define FMA4(acc, xs, wv) \
    acc.x = fmaf(xs, wv.x, acc.x); acc.y = fmaf(xs, wv.y, acc.y); \
    acc.z = fmaf(xs, wv.z, acc.z); acc.w = fmaf(xs, wv.w, acc.w);
__global__ __launch_bounds__(256) void xws_kernel(const float* __restrict__ x,
                                                  const float* __restrict__ W,
                                                  const float* __restrict__ dinv,
                                                  unsigned* __restrict__ xwsh) {
    __shared__ float sW[64 * OUT_C];       // 16 KB (k-half x 64 cols)
    __shared__ float sx[XN * SXS2];        // 8.5 KB (32 rows x 64 k + pad)
    const int t = threadIdx.x;
    const int n0 = blockIdx.x * XN;
    const int r  = t >> 4;
    const int cq = (t & 15) << 2;
    const int na = n0 + r, nb = na + 16;   // grid exact: always < N_NODES
    float4 a0 = make_float4(0.f, 0.f, 0.f, 0.f), a1 = a0;
#pragma unroll
    for (int ph = 0; ph < 2; ++ph) {
        const int kbase = ph << 6;
#pragma unroll
        for (int u = 0; u < 4; ++u) {
            int fi = t + u * 256;
            int row = fi >> 4, c4 = (fi & 15) << 2;
            *(float4*)&sW[(row << 6) + c4] =
                *(const float4*)&W[((kbase + row) << 6) + c4];
        }
#pragma unroll
        for (int u = 0; u < 2; ++u) {
            int fi = t + u * 256;
            int row = fi >> 4, c4 = (fi & 15) << 2;
            *(float4*)&sx[row * SXS2 + c4] =
                *(const float4*)&x[(long long)(n0 + row) * IN_C + kbase + c4];
        }
        __syncthreads();
#pragma unroll 8
        for (int k = 0; k < 64; ++k) {
            float x0 = sx[r * SXS2 + k];
            float x1 = sx[(r + 16) * SXS2 + k];
            float4 wv = *(const float4*)&sW[(k << 6) + cq];
            FMA4(a0, x0, wv);
            FMA4(a1, x1, wv);
        }
        __syncthreads();
    }
    {
        float di = dinv[na];
        uint2 o = make_uint2(pack_bf16x2(a0.x * di, a0.y * di),
                             pack_bf16x2(a0.z * di, a0.w * di));
        *(uint2*)&xwsh[(long long)na * 32 + ((t & 15) << 1)] = o;
    }
    {
        float di = dinv[nb];
        uint2 o = make_uint2(pack_bf16x2(a1.x * di, a1.y * di),
                             pack_bf16x2(a1.z * di, a1.w * di));
        *(uint2*)&xwsh[(long long)nb * 32 + ((t & 15) << 1)] = o;
    }
}

// ------- pull aggregation + fused epilogue: 2 nodes per wave ---------------
// (latency floor ~49 us, 5 variants converged)
__global__ __launch_bounds__(256) void aggnode_kernel(
    const int* __restrict__ rowbeg, const int* __restrict__ rowend,
    const int* __restrict__ srcs, const float* __restrict__ dinv,
    const unsigned* __restrict__ xwsh, const float* __restrict__ b,
    const float* __restrict__ Wc, const float* __restrict__ bc,
    float2* __restrict__ p, float2* __restrict__ q) {
    const int lane = threadIdx.x & 63;
    const int hl   = lane & 31;              // lane within node-half
    const int g    = hl >> 3;                // edge slot 0..3
    const int j    = hl & 7;                 // channel octet: ch 8j..8j+7
    const unsigned woff = (unsigned)(j << 2);
    const int node = blockIdx.x * 8 + ((threadIdx.x >> 6) << 1) + (lane >> 5);
    const int beg = rowbeg[node], end = rowend[node];
    const float di = dinv[node];                                   // hoisted
    const uint4 vsl = *(const uint4*)&xwsh[((unsigned)node << 5) + woff]; // hoisted
    float a0=0.f,a1=0.f,a2=0.f,a3=0.f,a4=0.f,a5=0.f,a6=0.f,a7=0.f;
    const int m1 = end - 1;
    for (int i = beg; i < end; i += 16) {
        int e0 = i + g, e1 = e0 + 4, e2 = e0 + 8, e3 = e0 + 12;
        int i0 = min(e0, m1), i1 = min(e1, m1), i2 = min(e2, m1), i3 = min(e3, m1);
        int s0 = srcs[i0], s1 = srcs[i1], s2 = srcs[i2], s3 = srcs[i3];
        float f0 = (e0 < end) ? 1.f : 0.f;
        float f1 = (e1 < end) ? 1.f : 0.f;
        float f2 = (e2 < end) ? 1.f : 0.f;
        float f3 = (e3 < end) ? 1.f : 0.f;
        uint4 v0 = *(const uint4*)&xwsh[((unsigned)s0 << 5) + woff];
        uint4 v1 = *(const uint4*)&xwsh[((unsigned)s1 << 5) + woff];
        uint4 v2 = *(const uint4*)&xwsh[((unsigned)s2 << 5) + woff];
        uint4 v3 = *(const uint4*)&xwsh[((unsigned)s3 << 5) + woff];
        a0 = fmaf(f0, bf_lo(v0.x), a0); a1 = fmaf(f0, bf_hi(v0.x), a1);
        a2 = fmaf(f0, bf_lo(v0.y), a2); a3 = fmaf(f0, bf_hi(v0.y), a3);
        a4 = fmaf(f0, bf_lo(v0.z), a4); a5 = fmaf(f0, bf_hi(v0.z), a5);
        a6 = fmaf(f0, bf_lo(v0.w), a6); a7 = fmaf(f0, bf_hi(v0.w), a7);
        a0 = fmaf(f1, bf_lo(v1.x), a0); a1 = fmaf(f1, bf_hi(v1.x), a1);
        a2 = fmaf(f1, bf_lo(v1.y), a2); a3 = fmaf(f1, bf_hi(v1.y), a3);
        a4 = fmaf(f1, bf_lo(v1.z), a4); a5 = fmaf(f1, bf_hi(v1.z), a5);
        a6 = fmaf(f1, bf_lo(v1.w), a6); a7 = fmaf(f1, bf_hi(v1.w), a7);
        a0 = fmaf(f2, bf_lo(v2.x), a0); a1 = fmaf(f2, bf_hi(v2.x), a1);
        a2 = fmaf(f2, bf_lo(v2.y), a2); a3 = fmaf(f2, bf_hi(v2.y), a3);
        a4 = fmaf(f2, bf_lo(v2.z), a4); a5 = fmaf(f2, bf_hi(v2.z), a5);
        a6 = fmaf(f2, bf_lo(v2.w), a6); a7 = fmaf(f2, bf_hi(v2.w), a7);
        a0 = fmaf(f3, bf_lo(v3.x), a0); a1 = fmaf(f3, bf_hi(v3.x), a1);
        a2 = fmaf(f3, bf_lo(v3.y), a2); a3 = fmaf(f3, bf_hi(v3.y), a3);
        a4 = fmaf(f3, bf_lo(v3.z), a4); a5 = fmaf(f3, bf_hi(v3.z), a5);
        a6 = fmaf(f3, bf_lo(v3.w), a6); a7 = fmaf(f3, bf_hi(v3.w), a7);
    }
    a0 += __shfl_xor(a0, 8); a0 += __shfl_xor(a0, 16);
    a1 += __shfl_xor(a1, 8); a1 += __shfl_xor(a1, 16);
    a2 += __shfl_xor(a2, 8); a2 += __shfl_xor(a2, 16);
    a3 += __shfl_xor(a3, 8); a3 += __shfl_xor(a3, 16);
    a4 += __shfl_xor(a4, 8); a4 += __shfl_xor(a4, 16);
    a5 += __shfl_xor(a5, 8); a5 += __shfl_xor(a5, 16);
    a6 += __shfl_xor(a6, 8); a6 += __shfl_xor(a6, 16);
    a7 += __shfl_xor(a7, 8); a7 += __shfl_xor(a7, 16);
    a0 += bf_lo(vsl.x); a1 += bf_hi(vsl.x);
    a2 += bf_lo(vsl.y); a3 += bf_hi(vsl.y);
    a4 += bf_lo(vsl.z); a5 += bf_hi(vsl.z);
    a6 += bf_lo(vsl.w); a7 += bf_hi(vsl.w);
    float4 bA = ((const float4*)b)[(j << 1)];
    float4 bB = ((const float4*)b)[(j << 1) + 1];
    float h0 = fmaxf(fmaf(di, a0, bA.x), 0.f);
    float h1 = fmaxf(fmaf(di, a1, bA.y), 0.f);
    float h2 = fmaxf(fmaf(di, a2, bA.z), 0.f);
    float h3 = fmaxf(fmaf(di, a3, bA.w), 0.f);
    float h4 = fmaxf(fmaf(di, a4, bB.x), 0.f);
    float h5 = fmaxf(fmaf(di, a5, bB.y), 0.f);
    float h6 = fmaxf(fmaf(di, a6, bB.z), 0.f);
    float h7 = fmaxf(fmaf(di, a7, bB.w), 0.f);
    const float4* WS = (const float4*)Wc;
    const float4* WD = (const float4*)(Wc + 2 * OUT_C);
    float p0, p1, q0, q1;
    {
        float4 w0 = WS[(j << 2)], w1 = WS[(j << 2) + 1];
        float4 w2 = WS[(j << 2) + 2], w3 = WS[(j << 2) + 3];
        p0 = h0 * w0.x + h1 * w0.z + h2 * w1.x + h3 * w1.z
           + h4 * w2.x + h5 * w2.z + h6 * w3.x + h7 * w3.z;
        p1 = h0 * w0.y + h1 * w0.w + h2 * w1.y + h3 * w1.w
           + h4 * w2.y + h5 * w2.w + h6 * w3.y + h7 * w3.w;
    }
    {
        float4 u0 = WD[(j << 2)], u1 = WD[(j << 2) + 1];
        float4 u2 = WD[(j << 2) + 2], u3 = WD[(j << 2) + 3];
        q0 = h0 * u0.x + h1 * u0.z + h2 * u1.x + h3 * u1.z
           + h4 * u2.x + h5 * u2.z + h6 * u3.x + h7 * u3.z;
        q1 = h0 * u0.y + h1 * u0.w + h2 * u1.y + h3 * u1.w
           + h4 * u2.y + h5 * u2.w + h6 * u3.y + h7 * u3.w;
    }
#pragma unroll
    for (int off = 1; off <= 4; off <<= 1) {
        p0 += __shfl_xor(p0, off); p1 += __shfl_xor(p1, off);
        q0 += __shfl_xor(q0, off); q1 += __shfl_xor(q1, off);
    }
    if (hl == 0) {
        p[node] = make_float2(p0 + bc[0], p1 + bc[1]);
        q[node] = make_float2(q0, q1);
    }
}

// ------------ edge outputs: out[e] = p[src] + q[dst], 2 edges/thread --------
// (R16-verified win)
__global__ __launch_bounds__(256) void edge_kernel(
    const int* __restrict__ ei, const int* __restrict__ nei,
    const float2* __restrict__ p, const float2* __restrict__ q,
    float4* __restrict__ out4) {
    int idx = blockIdx.x * blockDim.x + threadIdx.x;
    if (idx >= N_EDGES) return;                    // 2*N_EDGES/2 threads
    int e2 = idx * 2;
    const int *S, *D;
    int off;
    if (e2 < N_EDGES) { S = ei;  D = ei  + N_EDGES; off = e2; }
    else              { S = nei; D = nei + N_EDGES; off = e2 - N_EDGES; }
    int2 s2 = *(const int2*)&S[off];
    int2 d2 = *(const int2*)&D[off];
    float2 pa = p[s2.x], qa = q[d2.x];
    float2 pb = p[s2.y], qb = q[d2.y];
    out4[idx] = make_float4(pa.x + qa.x, pa.y + qa.y, pb.x + qb.x, pb.y + qb.y);
}

extern "C" void kernel_launch(void* const* d_in, const int* in_sizes, int n_in,
                              void* d_out, int out_size, void* d_ws, size_t ws_size,
                              hipStream_t stream) {
    const float* x   = (const float*)d_in[0];   // [N,128]
    const int*   ei  = (const int*)  d_in[1];   // [2,E]
    const int*   nei = (const int*)  d_in[2];   // [2,E]
    const float* W   = (const float*)d_in[3];   // [128,64]
    const float* b   = (const float*)d_in[4];   // [64]
    const float* Wc  = (const float*)d_in[5];   // [128,2]
    const float* bc  = (const float*)d_in[6];   // [2]

    // workspace (ints): end = 3902912 + 391*4608 = 5704640 ints = 22.8 MB
    int*      wsI    = (int*)d_ws;
    float*    dinv   = (float*)wsI;              // N           [0, 100352)
    unsigned* xwsh   = (unsigned*)(wsI + 100352);// N*32 bf16x2 [100352, 3300352)
    float*    p      = (float*)(wsI + 3300352);  // N*2         [3300352, 3501056)
    float*    q      = (float*)(wsI + 3501056);  // N*2         [3501056, 3701760)
    int*      cursor = wsI + 3701760;            // NSB=391     [3701760, 3702151)
    int*      rowbeg = wsI + 3702208;            // N           [3702208, 3802560)
    int*      rowend = wsI + 3802560;            // N           [3802560, 3902912)
    int*      sbuf   = wsI + 3902912;            // NSB*SCAP

    const int B = 256;
    hipMemsetAsync(cursor, 0, NSB * sizeof(int), stream);
    sorta_kernel<<<NABLK, 1024, 0, stream>>>(ei, cursor, sbuf);
    sortb_kernel<<<NSB, 1024, 0, stream>>>(cursor, sbuf, dinv, rowbeg, rowend);
    xws_kernel<<<N_NODES / XN, B, 0, stream>>>(x, W, dinv, xwsh);
    aggnode_kernel<<<N_NODES / 8, B, 0, stream>>>(rowbeg, rowend, sbuf, dinv, xwsh,
                                                  b, Wc, bc, (float2*)p, (float2*)q);
    edge_kernel<<<(N_EDGES + B - 1) / B, B, 0, stream>>>(
        ei, nei, (const float2*)p, (const float2*)q, (float4*)d_out);
}